// Round 14
// baseline (210.484 us; speedup 1.0000x reference)
//
#include <hip/hip_runtime.h>
#include <math.h>

// TransformerBlock N=2048, D=1024, H=16, DK=DV=64, FF=4096.
// Round 14: flash -> 1024-thread blocks, 4 q-waves x 4 kv-groups (group g
// takes kv-tiles jt%4==g): longest block's serial per-wave chain halves
// (16 -> 8 tiles). 2-round fp32 LDS tree merge (fits in Ks; -inf guarded).
// GEMMs / LN / prep unchanged from R13.

#define NTOK   2048
#define DMODEL 1024
#define NHEAD  16
#define DHEAD  64
#define DFF    4096
#define LNEPS  1e-5f

typedef unsigned int   u32;
typedef unsigned short u16;
typedef _Float16       f16;
typedef __attribute__((ext_vector_type(8))) short short8;
typedef __attribute__((ext_vector_type(4))) float f32x4;
typedef __attribute__((ext_vector_type(4))) _Float16 f16x4;

__device__ __forceinline__ u16 f2b(float f) {
    u32 b = __float_as_uint(f);
    b += 0x7FFFu + ((b >> 16) & 1u);   // RNE
    return (u16)(b >> 16);
}
__device__ __forceinline__ float b2f(u16 v) {
    return __uint_as_float((u32)v << 16);
}

#define AS1(p) ((const __attribute__((address_space(1))) u32*)(p))
#define AS3(p) ((__attribute__((address_space(3))) u32*)(p))

// ---------------- bf16 MFMA GEMM, 128x128 tile, BK=32, 2-phase dbuf --------
template<int RELU, int BIAS, int RESID, int OUT_BF16, int SPLITK>
__global__ __launch_bounds__(256) void mfma_gemm(
    const u16* __restrict__ A, int lda,
    const u16* __restrict__ Bt, int ldbt,
    void* __restrict__ Cp, int ldc, int Kc,
    const float* __restrict__ bias,
    const float* __restrict__ resid, int ldr,
    size_t pstride)
{
    __shared__ u16 As[2][128 * 32];
    __shared__ u16 Bs[2][128 * 32];

    const int tid = threadIdx.x;
    const int l = tid & 63, w = tid >> 6;
    const int row0 = blockIdx.y * 128, col0 = blockIdx.x * 128;
    const int kbase = (SPLITK > 1) ? blockIdx.z * Kc : 0;

    f32x4 acc[4][4];
    #pragma unroll
    for (int m = 0; m < 4; ++m)
        #pragma unroll
        for (int n = 0; n < 4; ++n)
            acc[m][n] = (f32x4){0.f, 0.f, 0.f, 0.f};

    const int srow = w * 32 + (l >> 2);
    const int skk  = (l & 3) * 8;
    const u16* Ag = A  + (size_t)(row0 + srow) * lda  + kbase + skk;
    const u16* Bg = Bt + (size_t)(col0 + srow) * ldbt + kbase + skk;

    const int fr  = l & 15;
    const int fk  = (l >> 4) * 8;
    const int ar0 = (w >> 1) * 64;
    const int bc0 = (w & 1) * 64;

    auto STAGE = [&](int buf, int k0) {
        char* AsB = (char*)&As[buf][0] + w * 2048;
        char* BsB = (char*)&Bs[buf][0] + w * 2048;
        __builtin_amdgcn_global_load_lds(AS1(Ag + k0),                     AS3(AsB),        16, 0, 0);
        __builtin_amdgcn_global_load_lds(AS1(Ag + k0 + (size_t)16 * lda),  AS3(AsB + 1024), 16, 0, 0);
        __builtin_amdgcn_global_load_lds(AS1(Bg + k0),                     AS3(BsB),        16, 0, 0);
        __builtin_amdgcn_global_load_lds(AS1(Bg + k0 + (size_t)16 * ldbt), AS3(BsB + 1024), 16, 0, 0);
    };

    STAGE(0, 0);
    int cur = 0;
    for (int k0 = 0; k0 < Kc; k0 += 32) {
        __syncthreads();
        if (k0 + 32 < Kc) STAGE(cur ^ 1, k0 + 32);

        short8 af[4], bfr[4];
        #pragma unroll
        for (int m = 0; m < 4; ++m)
            af[m] = *reinterpret_cast<const short8*>(&As[cur][(ar0 + m * 16 + fr) * 32 + fk]);
        #pragma unroll
        for (int n = 0; n < 4; ++n)
            bfr[n] = *reinterpret_cast<const short8*>(&Bs[cur][(bc0 + n * 16 + fr) * 32 + fk]);
        #pragma unroll
        for (int m = 0; m < 4; ++m)
            #pragma unroll
            for (int n = 0; n < 4; ++n)
                acc[m][n] = __builtin_amdgcn_mfma_f32_16x16x32_bf16(af[m], bfr[n], acc[m][n], 0, 0, 0);
        cur ^= 1;
    }

    if (SPLITK > 1) {
        f16* Pp = (f16*)Cp + blockIdx.z * pstride;
        #pragma unroll
        for (int m = 0; m < 4; ++m)
            #pragma unroll
            for (int n = 0; n < 4; ++n)
                #pragma unroll
                for (int r = 0; r < 4; ++r) {
                    int row = row0 + ar0 + m * 16 + (l >> 4) * 4 + r;
                    int col = col0 + bc0 + n * 16 + (l & 15);
                    Pp[(size_t)row * ldc + col] = (f16)acc[m][n][r];
                }
        return;
    }

    #pragma unroll
    for (int m = 0; m < 4; ++m) {
        #pragma unroll
        for (int n = 0; n < 4; ++n) {
            #pragma unroll
            for (int r = 0; r < 4; ++r) {
                int row = row0 + ar0 + m * 16 + (l >> 4) * 4 + r;
                int col = col0 + bc0 + n * 16 + (l & 15);
                float val = acc[m][n][r];
                if (BIAS)  val += bias[col];
                if (RESID) val += resid[(size_t)row * ldr + col];
                if (RELU)  val = fmaxf(val, 0.0f);
                if (OUT_BF16) ((u16*)Cp)[(size_t)row * ldc + col] = f2b(val);
                else          ((float*)Cp)[(size_t)row * ldc + col] = val;
            }
        }
    }
}

// ---------------- fused prep: x cast + all weight transposes ----------------
__device__ __forceinline__ void transpose_tile32(
    const float* __restrict__ in, int ldin,
    u16* __restrict__ out, int ldout, int r0, int c0)
{
    __shared__ float tile[32][33];
    int tx = threadIdx.x & 31, ty = threadIdx.x >> 5;
    #pragma unroll
    for (int i = 0; i < 4; ++i) {
        int r = ty + i * 8;
        tile[r][tx] = in[(size_t)(r0 + r) * ldin + c0 + tx];
    }
    __syncthreads();
    #pragma unroll
    for (int i = 0; i < 4; ++i) {
        int rr = ty + i * 8;
        out[(size_t)(c0 + rr) * ldout + r0 + tx] = f2b(tile[tx][rr]);
    }
}

__global__ __launch_bounds__(256) void prep_all(
    const float* __restrict__ x,
    const float* __restrict__ wq, const float* __restrict__ wk, const float* __restrict__ wv,
    const float* __restrict__ wo, const float* __restrict__ w1, const float* __restrict__ w2,
    u16* __restrict__ xb, u16* __restrict__ wqkvT, u16* __restrict__ woT,
    u16* __restrict__ w1T, u16* __restrict__ w2T)
{
    int b = blockIdx.x;
    if (b < 1024) {
        int i = (b * 256 + threadIdx.x) * 8;
        float4 v0 = *reinterpret_cast<const float4*>(x + i);
        float4 v1 = *reinterpret_cast<const float4*>(x + i + 4);
        ushort4 o0, o1;
        o0.x = f2b(v0.x); o0.y = f2b(v0.y); o0.z = f2b(v0.z); o0.w = f2b(v0.w);
        o1.x = f2b(v1.x); o1.y = f2b(v1.y); o1.z = f2b(v1.z); o1.w = f2b(v1.w);
        *reinterpret_cast<ushort4*>(xb + i)     = o0;
        *reinterpret_cast<ushort4*>(xb + i + 4) = o1;
    } else if (b < 4096) {
        int u = b - 1024;
        int z = u >> 6, t = u & 63;
        int p = z >> 4, hh = z & 15;
        const float* in = (p == 0 ? wq : p == 1 ? wk : wv) + (size_t)hh * DMODEL * DHEAD;
        u16* out = wqkvT + (size_t)(p * 1024 + hh * 64) * DMODEL;
        transpose_tile32(in, DHEAD, out, DMODEL, (t >> 1) * 32, (t & 1) * 32);
    } else if (b < 5120) {
        int u = b - 4096;
        transpose_tile32(wo, DMODEL, woT, DMODEL, (u >> 5) * 32, (u & 31) * 32);
    } else if (b < 9216) {
        int u = b - 5120;
        transpose_tile32(w1, DFF, w1T, DMODEL, (u >> 7) * 32, (u & 127) * 32);
    } else {
        int u = b - 9216;
        transpose_tile32(w2, DMODEL, w2T, DFF, (u >> 5) * 32, (u & 31) * 32);
    }
}

// ---------------- 16-wave 4-way-split-KV flash attention ----------
// 512 blocks (pair remap), 1024 threads = 4 q-waves x 4 kv-groups.
// Iteration s stages kv-tiles 4s..4s+3; group g computes tile 4s+g.
// Longest block: 8 serial tiles/wave (was 16). 2-round LDS tree merge.
__global__ __launch_bounds__(1024, 8) void flash_attn_mfma(
    const u16* __restrict__ qkvb, u16* __restrict__ concatb)
{
    const int bid = blockIdx.x;
    const int lo = bid & 255;
    int it = lo >> 3;
    int h  = lo & 7;
    if (bid >= 256) { it = 31 - it; h += 8; }

    const u16* qh = qkvb + h * DHEAD;
    const u16* kh = qkvb + DMODEL + h * DHEAD;
    const u16* vh = qkvb + 2 * DMODEL + h * DHEAD;
    const int LDQ = 3 * DMODEL;

    const float SC2  = 0.18033688f;    // 0.125 * log2(e)
    const float THR2 = 11.541560f;     // 8 * log2(e)

    __shared__ u16 Ks[4][64][72];
    __shared__ u16 Vt[4][64][72];

    const int tid = threadIdx.x;
    const int l = tid & 63, w = tid >> 6;      // w in 0..15
    const int grp = w >> 2, wq = w & 3;        // 4 kv-groups x 4 q-waves
    const int fr = l & 15, fg = l >> 4;

    short8 qf[2];
    {
        const u16* qp = qh + (size_t)(it * 64 + wq * 16 + fr) * LDQ + fg * 8;
        qf[0] = *reinterpret_cast<const short8*>(qp);
        qf[1] = *reinterpret_cast<const short8*>(qp + 32);
    }

    // staging over 1024 threads: 256 kv rows (4 tiles) per iteration
    const int kr  = tid >> 2;            // 0..255
    const int kb  = kr >> 6, krl = kr & 63;
    const int kc  = (tid & 3) * 16;      // 2 x short8 per thread
    const int vp  = tid >> 3;            // 0..127 row-pairs
    const int vb  = vp >> 5, vpl = vp & 31;
    const int vc  = (tid & 7) * 8;       // 8 dv per thread

    short8 kf0, kf1, vf0, vf1;
    auto PREFETCH = [&](int s) {
        const u16* kg = kh + (size_t)(s * 256 + kr) * LDQ + kc;
        kf0 = *reinterpret_cast<const short8*>(kg);
        kf1 = *reinterpret_cast<const short8*>(kg + 8);
        const u16* vg = vh + (size_t)(s * 256 + 2 * vp) * LDQ + vc;
        vf0 = *reinterpret_cast<const short8*>(vg);
        vf1 = *reinterpret_cast<const short8*>(vg + LDQ);
    };

    f32x4 o[4];
    #pragma unroll
    for (int n = 0; n < 4; ++n) o[n] = (f32x4){0.f, 0.f, 0.f, 0.f};
    float m_run = -INFINITY, l_run = 0.0f;     // base-2 log domain

    const int sA = fr + 16 * ((2 * fg) & 3);
    const int sB = sA + 16;
    const bool hi = (fg >= 2);

    char* VtSb = (char*)&Vt[vb][0][0];

    const int niter = (it >> 2) + 1;
    PREFETCH(0);

    for (int s = 0; s < niter; ++s) {
        __syncthreads();
        *reinterpret_cast<short8*>(&Ks[kb][krl][kc])     = kf0;
        *reinterpret_cast<short8*>(&Ks[kb][krl][kc + 8]) = kf1;
        #pragma unroll
        for (int i = 0; i < 8; ++i) {
            u32 word = (u32)(u16)vf0[i] | ((u32)(u16)vf1[i] << 16);
            int dv = vc + i;
            int off = 144 * dv + 16 * ((vpl >> 2) ^ ((dv >> 3) & 7)) + 4 * (vpl & 3);
            *reinterpret_cast<u32*>(VtSb + off) = word;
        }
        if (s + 1 < niter) PREFETCH(s + 1);
        __syncthreads();

        const int jt = 4 * s + grp;
        if (jt > it) continue;                 // this group idle this iter
        const u16 (*KsG)[72] = Ks[grp];
        char* VtG = (char*)&Vt[grp][0][0];

        // S^T = K @ Q^T : s_[n] holds S[kv = n*16 + fg*4 + r][q = fr]
        f32x4 s_[4];
        #pragma unroll
        for (int n = 0; n < 4; ++n) s_[n] = (f32x4){0.f, 0.f, 0.f, 0.f};
        __builtin_amdgcn_s_setprio(1);
        #pragma unroll
        for (int n = 0; n < 4; ++n) {
            #pragma unroll
            for (int ks = 0; ks < 2; ++ks) {
                short8 kfrag = *reinterpret_cast<const short8*>(&KsG[n * 16 + fr][ks * 32 + fg * 8]);
                s_[n] = __builtin_amdgcn_mfma_f32_16x16x32_bf16(kfrag, qf[ks], s_[n], 0, 0, 0);
            }
        }
        __builtin_amdgcn_s_setprio(0);

        // in-register online softmax (lane owns q-row fr), base-2, defer-max
        const bool diag = (jt == it);
        const int qrow_t = wq * 16 + fr;
        float sv[4][4];
        float pm = -INFINITY;
        #pragma unroll
        for (int n = 0; n < 4; ++n)
            #pragma unroll
            for (int r = 0; r < 4; ++r) {
                float v = s_[n][r] * SC2;
                if (diag && (n * 16 + fg * 4 + r) > qrow_t) v = -INFINITY;
                sv[n][r] = v;
                pm = fmaxf(pm, v);
            }
        pm = fmaxf(pm, __shfl_xor(pm, 16));
        pm = fmaxf(pm, __shfl_xor(pm, 32));
        if (!__all(pm <= m_run + THR2)) {
            float mnew = fmaxf(m_run, pm);
            float corr = exp2f(m_run - mnew);
            l_run *= corr;
            #pragma unroll
            for (int n = 0; n < 4; ++n) {
                o[n][0] *= corr; o[n][1] *= corr; o[n][2] *= corr; o[n][3] *= corr;
            }
            m_run = mnew;
        }
        float rs = 0.0f;
        float pp[4][4];
        #pragma unroll
        for (int n = 0; n < 4; ++n)
            #pragma unroll
            for (int r = 0; r < 4; ++r) {
                float pv = exp2f(sv[n][r] - m_run);
                pp[n][r] = pv;
                rs += pv;
            }
        rs += __shfl_xor(rs, 16);
        rs += __shfl_xor(rs, 32);
        l_run += rs;

        // pack P to bf16 pairs (truncation)
        u32 pk[4][2];
        #pragma unroll
        for (int n = 0; n < 4; ++n) {
            pk[n][0] = (__float_as_uint(pp[n][0]) >> 16) | (__float_as_uint(pp[n][1]) & 0xFFFF0000u);
            pk[n][1] = (__float_as_uint(pp[n][2]) >> 16) | (__float_as_uint(pp[n][3]) & 0xFFFF0000u);
        }

        // PV with in-register P redistribution
        __builtin_amdgcn_s_setprio(1);
        #pragma unroll
        for (int ks = 0; ks < 2; ++ks) {
            u32 a0 = __shfl(pk[2 * ks][0], sA);
            u32 a1 = __shfl(pk[2 * ks][1], sA);
            u32 a2 = __shfl(pk[2 * ks][0], sB);
            u32 a3 = __shfl(pk[2 * ks][1], sB);
            u32 b0 = __shfl(pk[2 * ks + 1][0], sA);
            u32 b1 = __shfl(pk[2 * ks + 1][1], sA);
            u32 b2 = __shfl(pk[2 * ks + 1][0], sB);
            u32 b3 = __shfl(pk[2 * ks + 1][1], sB);
            union { u32 u[4]; short8 s8; } pb;
            pb.u[0] = hi ? b0 : a0;
            pb.u[1] = hi ? b1 : a1;
            pb.u[2] = hi ? b2 : a2;
            pb.u[3] = hi ? b3 : a3;
            #pragma unroll
            for (int n = 0; n < 4; ++n) {
                int dv = n * 16 + fr;
                const short8* vfrag = reinterpret_cast<const short8*>(
                    VtG + 144 * dv + 16 * ((ks * 4 + fg) ^ ((dv >> 3) & 7)));
                o[n] = __builtin_amdgcn_mfma_f32_16x16x32_bf16(*vfrag, pb.s8, o[n], 0, 0, 0);
            }
        }
        __builtin_amdgcn_s_setprio(0);
    }

    // ---- 2-round tree merge via LDS (overlay on Ks; fp32) ----
    // round 1: grp1 -> grp0, grp3 -> grp2;  round 2: grp2 -> grp0.
    float* mrg = reinterpret_cast<float*>(&Ks[0][0][0]);
    const int slotL = (wq * 64 + l) * 18;          // 4*64*18 = 4608 floats
    const int slotH = (256 + wq * 64 + l) * 18;    // total 9216 floats = 36864B

    auto WRITE = [&](int slot) {
        #pragma unroll
        for (int n = 0; n < 4; ++n)
            #pragma unroll
            for (int r = 0; r < 4; ++r)
                mrg[slot + n * 4 + r] = o[n][r];
        mrg[slot + 16] = m_run;
        mrg[slot + 17] = l_run;
    };
    auto MERGE = [&](int slot) {
        float m2 = mrg[slot + 16];
        if (m2 > -INFINITY) {                     // skip empty partials
            float l2 = mrg[slot + 17];
            float mstar = fmaxf(m_run, m2);
            float cA = exp2f(m_run - mstar);
            float cB = exp2f(m2 - mstar);
            #pragma unroll
            for (int n = 0; n < 4; ++n)
                #pragma unroll
                for (int r = 0; r < 4; ++r)
                    o[n][r] = o[n][r] * cA + mrg[slot + n * 4 + r] * cB;
            l_run = l_run * cA + l2 * cB;
            m_run = mstar;
        }
    };

    __syncthreads();
    if (grp == 1) WRITE(slotL);
    if (grp == 3) WRITE(slotH);
    __syncthreads();
    if (grp == 0) MERGE(slotL);
    if (grp == 2) MERGE(slotH);
    __syncthreads();
    if (grp == 2) WRITE(slotL);
    __syncthreads();
    if (grp == 0) {
        MERGE(slotL);
        float inv = 1.0f / l_run;
        int qrow = it * 64 + wq * 16 + fr;
        #pragma unroll
        for (int n = 0; n < 4; ++n)
            #pragma unroll
            for (int r = 0; r < 4; ++r)
                concatb[(size_t)qrow * DMODEL + h * DHEAD + n * 16 + fg * 4 + r] = f2b(o[n][r] * inv);
    }
}

// ---------------- fused fp16-partial-reduce + LayerNorm ----------------
template<int NPART, int RELUB, int OUTF, int DUAL, int BASEBF16>
__global__ __launch_bounds__(256) void ln_fuse(
    const f16* __restrict__ P, size_t pstride,
    const void* __restrict__ basev,
    const float* __restrict__ bias2,
    const float* __restrict__ g, const float* __restrict__ b,
    float* __restrict__ out, u16* __restrict__ outb)
{
    int row = blockIdx.x, tid = threadIdx.x;
    __shared__ float red[256];
    size_t off = (size_t)row * DMODEL + tid * 4;

    float a0 = 0.f, a1 = 0.f, a2 = 0.f, a3 = 0.f;
    #pragma unroll
    for (int p = 0; p < NPART; ++p) {
        f16x4 t = *reinterpret_cast<const f16x4*>(P + (size_t)p * pstride + off);
        a0 += (float)t.x; a1 += (float)t.y; a2 += (float)t.z; a3 += (float)t.w;
    }
    if (RELUB) {
        float4 bb = *reinterpret_cast<const float4*>(bias2 + tid * 4);
        a0 = fmaxf(a0 + bb.x, 0.0f); a1 = fmaxf(a1 + bb.y, 0.0f);
        a2 = fmaxf(a2 + bb.z, 0.0f); a3 = fmaxf(a3 + bb.w, 0.0f);
    }
    float vals[4];
    if (BASEBF16) {
        ushort4 bs = *reinterpret_cast<const ushort4*>((const u16*)basev + off);
        vals[0] = a0 + b2f(bs.x); vals[1] = a1 + b2f(bs.y);
        vals[2] = a2 + b2f(bs.z); vals[3] = a3 + b2f(bs.w);
    } else {
        float4 bs = *reinterpret_cast<const float4*>((const float*)basev + off);
        vals[0] = a0 + bs.x; vals[1] = a1 + bs.y; vals[2] = a2 + bs.z; vals[3] = a3 + bs.w;
    }

    float s = vals[0] + vals[1] + vals[2] + vals[3];
    red[tid] = s; __syncthreads();
    for (int st = 128; st > 0; st >>= 1) { if (tid < st) red[tid] += red[tid + st]; __syncthreads(); }
    float mu = red[0] * (1.0f / DMODEL);
    __syncthreads();

    float vs = 0.0f;
    #pragma unroll
    for (int i = 0; i < 4; ++i) { float d = vals[i] - mu; vs += d * d; }
    red[tid] = vs; __syncthreads();
    for (int st = 128; st > 0; st >>= 1) { if (tid < st) red[tid] += red[tid + st]; __syncthreads(); }
    float rstd = rsqrtf(red[0] * (1.0f / DMODEL) + LNEPS);

    float4 gv = *reinterpret_cast<const float4*>(g + tid * 4);
    float4 bv = *reinterpret_cast<const float4*>(b + tid * 4);
    float gs[4] = {gv.x, gv.y, gv.z, gv.w};
    float bsc[4] = {bv.x, bv.y, bv.z, bv.w};
    #pragma unroll
    for (int i = 0; i < 4; ++i) {
        float r = (vals[i] - mu) * rstd * gs[i] + bsc[i];
        if (OUTF) out[off + i] = r;
        if (DUAL) outb[off + i] = f2b(r);
    }
}

// ---------------- launch ----------------
extern "C" void kernel_launch(void* const* d_in, const int* in_sizes, int n_in,
                              void* d_out, int out_size, void* d_ws, size_t ws_size,
                              hipStream_t stream)
{
    const float* x    = (const float*)d_in[0];
    const float* wq   = (const float*)d_in[1];
    const float* wk   = (const float*)d_in[2];
    const float* wv   = (const float*)d_in[3];
    const float* wo   = (const float*)d_in[4];
    const float* ln1g = (const float*)d_in[5];
    const float* ln1b = (const float*)d_in[6];
    const float* w1   = (const float*)d_in[7];
    const float* b1   = (const float*)d_in[8];
    const float* w2   = (const float*)d_in[9];
    const float* b2   = (const float*)d_in[10];
    const float* ln2g = (const float*)d_in[11];
    const float* ln2b = (const float*)d_in[12];
    float* out = (float*)d_out;

    // 64 MB workspace (liveness-checked):
    //  [0,8)   w2T (prep -> ffn2)          [8,16)  w1T (prep -> ffn1)
    //  [16,18) woT (prep -> oproj)         [18,24) wqkvT (prep -> qkv)
    //  [24,28) xb (prep -> qkv); then ff1b [24,40) (ffn1 -> ffn2)
    //  [28,40) qkvb (qkv -> flash)         [40,44) concatb (flash -> oproj)
    //  [44,60) Ph/Fh fp16 x4 partials      [60,64) h1b (LN1 -> ffn1, LN2 base)
    char* ws = (char*)d_ws;
    const size_t MB = 1024 * 1024;
    u16* w2T     = (u16*)(ws + 0 * MB);
    u16* w1T     = (u16*)(ws + 8 * MB);
    u16* woT     = (u16*)(ws + 16 * MB);
    u16* wqkvT   = (u16*)(ws + 18 * MB);
    u16* xb      = (u16*)(ws + 24 * MB);
    u16* ff1b    = (u16*)(ws + 24 * MB);
    u16* qkvb    = (u16*)(ws + 28 * MB);
    u16* concatb = (u16*)(ws + 40 * MB);
    f16* Ph      = (f16*)(ws + 44 * MB);
    f16* Fh      = (f16*)(ws + 44 * MB);
    u16* h1b     = (u16*)(ws + 60 * MB);

    const size_t PSTRIDE = (size_t)NTOK * DMODEL;

    dim3 blk(256);

    prep_all<<<dim3(13312), blk, 0, stream>>>(x, wq, wk, wv, wo, w1, w2,
                                              xb, wqkvT, woT, w1T, w2T);

    mfma_gemm<0,0,0,1,1><<<dim3(24, 16), blk, 0, stream>>>(
        xb, DMODEL, wqkvT, DMODEL, qkvb, 3 * DMODEL, DMODEL, nullptr, nullptr, 0, 0);
    flash_attn_mfma<<<dim3(512), dim3(1024), 0, stream>>>(qkvb, concatb);
    mfma_gemm<0,0,0,0,4><<<dim3(8, 16, 4), blk, 0, stream>>>(
        concatb, DMODEL, woT, DMODEL, Ph, DMODEL, 256, nullptr, nullptr, 0, PSTRIDE);
    ln_fuse<4,0,0,1,0><<<dim3(NTOK), blk, 0, stream>>>(
        Ph, PSTRIDE, x, nullptr, ln1g, ln1b, nullptr, h1b);
    mfma_gemm<1,1,0,1,1><<<dim3(32, 16), blk, 0, stream>>>(
        h1b, DMODEL, w1T, DMODEL, ff1b, DFF, DMODEL, b1, nullptr, 0, 0);
    mfma_gemm<0,0,0,0,4><<<dim3(8, 16, 4), blk, 0, stream>>>(
        ff1b, DFF, w2T, DFF, Fh, DMODEL, 1024, nullptr, nullptr, 0, PSTRIDE);
    ln_fuse<4,1,1,0,1><<<dim3(NTOK), blk, 0, stream>>>(
        Fh, PSTRIDE, h1b, b2, ln2g, ln2b, out, nullptr);
}

// Round 15
// 162.310 us; speedup vs baseline: 1.2968x; 1.2968x over previous
//
#include <hip/hip_runtime.h>
#include <math.h>

// TransformerBlock N=2048, D=1024, H=16, DK=DV=64, FF=4096.
// Round 15: exact revert to R13 (best: 162.4us). R14's 16-wave flash
// (launch_bounds(1024,8)) forced VGPR->32, full spill, flash 39->95us.
// R13 flash: 512 blocks x 512 threads (8 waves, 2 kv-groups), no min-waves
// clause (VGPR 60, no spill), base-2 softmax, defer-max, fp16 split-K
// partials, fused prep.

#define NTOK   2048
#define DMODEL 1024
#define NHEAD  16
#define DHEAD  64
#define DFF    4096
#define LNEPS  1e-5f

typedef unsigned int   u32;
typedef unsigned short u16;
typedef _Float16       f16;
typedef __attribute__((ext_vector_type(8))) short short8;
typedef __attribute__((ext_vector_type(4))) float f32x4;
typedef __attribute__((ext_vector_type(4))) _Float16 f16x4;

__device__ __forceinline__ u16 f2b(float f) {
    u32 b = __float_as_uint(f);
    b += 0x7FFFu + ((b >> 16) & 1u);   // RNE
    return (u16)(b >> 16);
}
__device__ __forceinline__ float b2f(u16 v) {
    return __uint_as_float((u32)v << 16);
}

#define AS1(p) ((const __attribute__((address_space(1))) u32*)(p))
#define AS3(p) ((__attribute__((address_space(3))) u32*)(p))

// ---------------- bf16 MFMA GEMM, 128x128 tile, BK=32, 2-phase dbuf --------
template<int RELU, int BIAS, int RESID, int OUT_BF16, int SPLITK>
__global__ __launch_bounds__(256) void mfma_gemm(
    const u16* __restrict__ A, int lda,
    const u16* __restrict__ Bt, int ldbt,
    void* __restrict__ Cp, int ldc, int Kc,
    const float* __restrict__ bias,
    const float* __restrict__ resid, int ldr,
    size_t pstride)
{
    __shared__ u16 As[2][128 * 32];
    __shared__ u16 Bs[2][128 * 32];

    const int tid = threadIdx.x;
    const int l = tid & 63, w = tid >> 6;
    const int row0 = blockIdx.y * 128, col0 = blockIdx.x * 128;
    const int kbase = (SPLITK > 1) ? blockIdx.z * Kc : 0;

    f32x4 acc[4][4];
    #pragma unroll
    for (int m = 0; m < 4; ++m)
        #pragma unroll
        for (int n = 0; n < 4; ++n)
            acc[m][n] = (f32x4){0.f, 0.f, 0.f, 0.f};

    const int srow = w * 32 + (l >> 2);
    const int skk  = (l & 3) * 8;
    const u16* Ag = A  + (size_t)(row0 + srow) * lda  + kbase + skk;
    const u16* Bg = Bt + (size_t)(col0 + srow) * ldbt + kbase + skk;

    const int fr  = l & 15;
    const int fk  = (l >> 4) * 8;
    const int ar0 = (w >> 1) * 64;
    const int bc0 = (w & 1) * 64;

    auto STAGE = [&](int buf, int k0) {
        char* AsB = (char*)&As[buf][0] + w * 2048;
        char* BsB = (char*)&Bs[buf][0] + w * 2048;
        __builtin_amdgcn_global_load_lds(AS1(Ag + k0),                     AS3(AsB),        16, 0, 0);
        __builtin_amdgcn_global_load_lds(AS1(Ag + k0 + (size_t)16 * lda),  AS3(AsB + 1024), 16, 0, 0);
        __builtin_amdgcn_global_load_lds(AS1(Bg + k0),                     AS3(BsB),        16, 0, 0);
        __builtin_amdgcn_global_load_lds(AS1(Bg + k0 + (size_t)16 * ldbt), AS3(BsB + 1024), 16, 0, 0);
    };

    STAGE(0, 0);
    int cur = 0;
    for (int k0 = 0; k0 < Kc; k0 += 32) {
        __syncthreads();
        if (k0 + 32 < Kc) STAGE(cur ^ 1, k0 + 32);

        short8 af[4], bfr[4];
        #pragma unroll
        for (int m = 0; m < 4; ++m)
            af[m] = *reinterpret_cast<const short8*>(&As[cur][(ar0 + m * 16 + fr) * 32 + fk]);
        #pragma unroll
        for (int n = 0; n < 4; ++n)
            bfr[n] = *reinterpret_cast<const short8*>(&Bs[cur][(bc0 + n * 16 + fr) * 32 + fk]);
        #pragma unroll
        for (int m = 0; m < 4; ++m)
            #pragma unroll
            for (int n = 0; n < 4; ++n)
                acc[m][n] = __builtin_amdgcn_mfma_f32_16x16x32_bf16(af[m], bfr[n], acc[m][n], 0, 0, 0);
        cur ^= 1;
    }

    if (SPLITK > 1) {
        f16* Pp = (f16*)Cp + blockIdx.z * pstride;
        #pragma unroll
        for (int m = 0; m < 4; ++m)
            #pragma unroll
            for (int n = 0; n < 4; ++n)
                #pragma unroll
                for (int r = 0; r < 4; ++r) {
                    int row = row0 + ar0 + m * 16 + (l >> 4) * 4 + r;
                    int col = col0 + bc0 + n * 16 + (l & 15);
                    Pp[(size_t)row * ldc + col] = (f16)acc[m][n][r];
                }
        return;
    }

    #pragma unroll
    for (int m = 0; m < 4; ++m) {
        #pragma unroll
        for (int n = 0; n < 4; ++n) {
            #pragma unroll
            for (int r = 0; r < 4; ++r) {
                int row = row0 + ar0 + m * 16 + (l >> 4) * 4 + r;
                int col = col0 + bc0 + n * 16 + (l & 15);
                float val = acc[m][n][r];
                if (BIAS)  val += bias[col];
                if (RESID) val += resid[(size_t)row * ldr + col];
                if (RELU)  val = fmaxf(val, 0.0f);
                if (OUT_BF16) ((u16*)Cp)[(size_t)row * ldc + col] = f2b(val);
                else          ((float*)Cp)[(size_t)row * ldc + col] = val;
            }
        }
    }
}

// ---------------- fused prep: x cast + all weight transposes ----------------
__device__ __forceinline__ void transpose_tile32(
    const float* __restrict__ in, int ldin,
    u16* __restrict__ out, int ldout, int r0, int c0)
{
    __shared__ float tile[32][33];
    int tx = threadIdx.x & 31, ty = threadIdx.x >> 5;
    #pragma unroll
    for (int i = 0; i < 4; ++i) {
        int r = ty + i * 8;
        tile[r][tx] = in[(size_t)(r0 + r) * ldin + c0 + tx];
    }
    __syncthreads();
    #pragma unroll
    for (int i = 0; i < 4; ++i) {
        int rr = ty + i * 8;
        out[(size_t)(c0 + rr) * ldout + r0 + tx] = f2b(tile[tx][rr]);
    }
}

__global__ __launch_bounds__(256) void prep_all(
    const float* __restrict__ x,
    const float* __restrict__ wq, const float* __restrict__ wk, const float* __restrict__ wv,
    const float* __restrict__ wo, const float* __restrict__ w1, const float* __restrict__ w2,
    u16* __restrict__ xb, u16* __restrict__ wqkvT, u16* __restrict__ woT,
    u16* __restrict__ w1T, u16* __restrict__ w2T)
{
    int b = blockIdx.x;
    if (b < 1024) {
        int i = (b * 256 + threadIdx.x) * 8;
        float4 v0 = *reinterpret_cast<const float4*>(x + i);
        float4 v1 = *reinterpret_cast<const float4*>(x + i + 4);
        ushort4 o0, o1;
        o0.x = f2b(v0.x); o0.y = f2b(v0.y); o0.z = f2b(v0.z); o0.w = f2b(v0.w);
        o1.x = f2b(v1.x); o1.y = f2b(v1.y); o1.z = f2b(v1.z); o1.w = f2b(v1.w);
        *reinterpret_cast<ushort4*>(xb + i)     = o0;
        *reinterpret_cast<ushort4*>(xb + i + 4) = o1;
    } else if (b < 4096) {
        int u = b - 1024;
        int z = u >> 6, t = u & 63;
        int p = z >> 4, hh = z & 15;
        const float* in = (p == 0 ? wq : p == 1 ? wk : wv) + (size_t)hh * DMODEL * DHEAD;
        u16* out = wqkvT + (size_t)(p * 1024 + hh * 64) * DMODEL;
        transpose_tile32(in, DHEAD, out, DMODEL, (t >> 1) * 32, (t & 1) * 32);
    } else if (b < 5120) {
        int u = b - 4096;
        transpose_tile32(wo, DMODEL, woT, DMODEL, (u >> 5) * 32, (u & 31) * 32);
    } else if (b < 9216) {
        int u = b - 5120;
        transpose_tile32(w1, DFF, w1T, DMODEL, (u >> 7) * 32, (u & 127) * 32);
    } else {
        int u = b - 9216;
        transpose_tile32(w2, DMODEL, w2T, DFF, (u >> 5) * 32, (u & 31) * 32);
    }
}

// ---------------- 8-wave split-KV swapped-operand flash attention ----------
// 512 blocks (pair remap), 512 threads. grp = w>>2; iteration s stages 4
// kv-tiles; grp g computes tiles 4s+2g, 4s+2g+1 sequentially. Base-2
// softmax, defer-max. NO min-waves clause: body needs ~60 VGPR (R12/R14
// lesson: forcing more waves/EU spills and is 1.4-2.4x slower).
__global__ __launch_bounds__(512) void flash_attn_mfma(
    const u16* __restrict__ qkvb, u16* __restrict__ concatb)
{
    const int bid = blockIdx.x;
    const int lo = bid & 255;
    int it = lo >> 3;
    int h  = lo & 7;
    if (bid >= 256) { it = 31 - it; h += 8; }

    const u16* qh = qkvb + h * DHEAD;
    const u16* kh = qkvb + DMODEL + h * DHEAD;
    const u16* vh = qkvb + 2 * DMODEL + h * DHEAD;
    const int LDQ = 3 * DMODEL;

    const float SC2  = 0.18033688f;    // 0.125 * log2(e)
    const float THR2 = 11.541560f;     // 8 * log2(e)

    __shared__ u16 Ks[4][64][72];
    __shared__ u16 Vt[4][64][72];

    const int tid = threadIdx.x;
    const int l = tid & 63, w = tid >> 6;
    const int grp = w >> 2, wq = w & 3;
    const int fr = l & 15, fg = l >> 4;

    short8 qf[2];
    {
        const u16* qp = qh + (size_t)(it * 64 + wq * 16 + fr) * LDQ + fg * 8;
        qf[0] = *reinterpret_cast<const short8*>(qp);
        qf[1] = *reinterpret_cast<const short8*>(qp + 32);
    }

    const int kr  = tid >> 1;
    const int kb  = kr >> 6, krl = kr & 63;
    const int kc  = (tid & 1) * 32;
    const int vp  = tid >> 2;
    const int vb  = vp >> 5, vpl = vp & 31;
    const int vc  = (tid & 3) * 16;

    short8 kf[4], vf0[2], vf1[2];
    auto PREFETCH = [&](int s) {
        const u16* kg = kh + (size_t)(s * 256 + kr) * LDQ + kc;
        kf[0] = *reinterpret_cast<const short8*>(kg);
        kf[1] = *reinterpret_cast<const short8*>(kg + 8);
        kf[2] = *reinterpret_cast<const short8*>(kg + 16);
        kf[3] = *reinterpret_cast<const short8*>(kg + 24);
        const u16* vg = vh + (size_t)(s * 256 + 2 * vp) * LDQ + vc;
        vf0[0] = *reinterpret_cast<const short8*>(vg);
        vf0[1] = *reinterpret_cast<const short8*>(vg + 8);
        vf1[0] = *reinterpret_cast<const short8*>(vg + LDQ);
        vf1[1] = *reinterpret_cast<const short8*>(vg + LDQ + 8);
    };

    f32x4 o[4];
    #pragma unroll
    for (int n = 0; n < 4; ++n) o[n] = (f32x4){0.f, 0.f, 0.f, 0.f};
    float m_run = -INFINITY, l_run = 0.0f;     // base-2 log domain

    const int sA = fr + 16 * ((2 * fg) & 3);
    const int sB = sA + 16;
    const bool hi = (fg >= 2);

    char* VtSb = (char*)&Vt[vb][0][0];

    const int niter = (it >> 2) + 1;
    PREFETCH(0);

    for (int s = 0; s < niter; ++s) {
        __syncthreads();
        *reinterpret_cast<short8*>(&Ks[kb][krl][kc +  0]) = kf[0];
        *reinterpret_cast<short8*>(&Ks[kb][krl][kc +  8]) = kf[1];
        *reinterpret_cast<short8*>(&Ks[kb][krl][kc + 16]) = kf[2];
        *reinterpret_cast<short8*>(&Ks[kb][krl][kc + 24]) = kf[3];
        #pragma unroll
        for (int c2 = 0; c2 < 2; ++c2) {
            #pragma unroll
            for (int i = 0; i < 8; ++i) {
                u32 word = (u32)(u16)vf0[c2][i] | ((u32)(u16)vf1[c2][i] << 16);
                int dv = vc + c2 * 8 + i;
                int off = 144 * dv + 16 * ((vpl >> 2) ^ ((dv >> 3) & 7)) + 4 * (vpl & 3);
                *reinterpret_cast<u32*>(VtSb + off) = word;
            }
        }
        if (s + 1 < niter) PREFETCH(s + 1);
        __syncthreads();

        #pragma unroll
        for (int t = 0; t < 2; ++t) {
            const int jt = 4 * s + 2 * grp + t;
            if (jt > it) continue;
            const int buf = 2 * grp + t;
            const u16 (*KsG)[72] = Ks[buf];
            char* VtG = (char*)&Vt[buf][0][0];

            f32x4 s_[4];
            #pragma unroll
            for (int n = 0; n < 4; ++n) s_[n] = (f32x4){0.f, 0.f, 0.f, 0.f};
            __builtin_amdgcn_s_setprio(1);
            #pragma unroll
            for (int n = 0; n < 4; ++n) {
                #pragma unroll
                for (int ks = 0; ks < 2; ++ks) {
                    short8 kfrag = *reinterpret_cast<const short8*>(&KsG[n * 16 + fr][ks * 32 + fg * 8]);
                    s_[n] = __builtin_amdgcn_mfma_f32_16x16x32_bf16(kfrag, qf[ks], s_[n], 0, 0, 0);
                }
            }
            __builtin_amdgcn_s_setprio(0);

            const bool diag = (jt == it);
            const int qrow_t = wq * 16 + fr;
            float sv[4][4];
            float pm = -INFINITY;
            #pragma unroll
            for (int n = 0; n < 4; ++n)
                #pragma unroll
                for (int r = 0; r < 4; ++r) {
                    float v = s_[n][r] * SC2;
                    if (diag && (n * 16 + fg * 4 + r) > qrow_t) v = -INFINITY;
                    sv[n][r] = v;
                    pm = fmaxf(pm, v);
                }
            pm = fmaxf(pm, __shfl_xor(pm, 16));
            pm = fmaxf(pm, __shfl_xor(pm, 32));
            if (!__all(pm <= m_run + THR2)) {
                float mnew = fmaxf(m_run, pm);
                float corr = exp2f(m_run - mnew);
                l_run *= corr;
                #pragma unroll
                for (int n = 0; n < 4; ++n) {
                    o[n][0] *= corr; o[n][1] *= corr; o[n][2] *= corr; o[n][3] *= corr;
                }
                m_run = mnew;
            }
            float rs = 0.0f;
            float pp[4][4];
            #pragma unroll
            for (int n = 0; n < 4; ++n)
                #pragma unroll
                for (int r = 0; r < 4; ++r) {
                    float pv = exp2f(sv[n][r] - m_run);
                    pp[n][r] = pv;
                    rs += pv;
                }
            rs += __shfl_xor(rs, 16);
            rs += __shfl_xor(rs, 32);
            l_run += rs;

            u32 pk[4][2];
            #pragma unroll
            for (int n = 0; n < 4; ++n) {
                pk[n][0] = (__float_as_uint(pp[n][0]) >> 16) | (__float_as_uint(pp[n][1]) & 0xFFFF0000u);
                pk[n][1] = (__float_as_uint(pp[n][2]) >> 16) | (__float_as_uint(pp[n][3]) & 0xFFFF0000u);
            }

            __builtin_amdgcn_s_setprio(1);
            #pragma unroll
            for (int ks = 0; ks < 2; ++ks) {
                u32 a0 = __shfl(pk[2 * ks][0], sA);
                u32 a1 = __shfl(pk[2 * ks][1], sA);
                u32 a2 = __shfl(pk[2 * ks][0], sB);
                u32 a3 = __shfl(pk[2 * ks][1], sB);
                u32 b0 = __shfl(pk[2 * ks + 1][0], sA);
                u32 b1 = __shfl(pk[2 * ks + 1][1], sA);
                u32 b2 = __shfl(pk[2 * ks + 1][0], sB);
                u32 b3 = __shfl(pk[2 * ks + 1][1], sB);
                union { u32 u[4]; short8 s8; } pb;
                pb.u[0] = hi ? b0 : a0;
                pb.u[1] = hi ? b1 : a1;
                pb.u[2] = hi ? b2 : a2;
                pb.u[3] = hi ? b3 : a3;
                #pragma unroll
                for (int n = 0; n < 4; ++n) {
                    int dv = n * 16 + fr;
                    const short8* vfrag = reinterpret_cast<const short8*>(
                        VtG + 144 * dv + 16 * ((ks * 4 + fg) ^ ((dv >> 3) & 7)));
                    o[n] = __builtin_amdgcn_mfma_f32_16x16x32_bf16(*vfrag, pb.s8, o[n], 0, 0, 0);
                }
            }
            __builtin_amdgcn_s_setprio(0);
        }
    }

    // ---- merge group B partials into group A via LDS (overlay on Ks) ----
    __syncthreads();
    float* mrg = reinterpret_cast<float*>(&Ks[0][0][0]);
    const int slot = (wq * 64 + l) * 18;
    if (grp == 1) {
        #pragma unroll
        for (int n = 0; n < 4; ++n)
            #pragma unroll
            for (int r = 0; r < 4; ++r)
                mrg[slot + n * 4 + r] = o[n][r];
        mrg[slot + 16] = m_run;
        mrg[slot + 17] = l_run;
    }
    __syncthreads();
    if (grp == 0) {
        float mB = mrg[slot + 16], lB = mrg[slot + 17];
        float mstar = fmaxf(m_run, mB);
        float cA = exp2f(m_run - mstar);
        float cB = exp2f(mB - mstar);
        float inv = 1.0f / (l_run * cA + lB * cB);
        int qrow = it * 64 + wq * 16 + fr;
        #pragma unroll
        for (int n = 0; n < 4; ++n)
            #pragma unroll
            for (int r = 0; r < 4; ++r) {
                float val = (o[n][r] * cA + mrg[slot + n * 4 + r] * cB) * inv;
                concatb[(size_t)qrow * DMODEL + h * DHEAD + n * 16 + fg * 4 + r] = f2b(val);
            }
    }
}

// ---------------- fused fp16-partial-reduce + LayerNorm ----------------
template<int NPART, int RELUB, int OUTF, int DUAL, int BASEBF16>
__global__ __launch_bounds__(256) void ln_fuse(
    const f16* __restrict__ P, size_t pstride,
    const void* __restrict__ basev,
    const float* __restrict__ bias2,
    const float* __restrict__ g, const float* __restrict__ b,
    float* __restrict__ out, u16* __restrict__ outb)
{
    int row = blockIdx.x, tid = threadIdx.x;
    __shared__ float red[256];
    size_t off = (size_t)row * DMODEL + tid * 4;

    float a0 = 0.f, a1 = 0.f, a2 = 0.f, a3 = 0.f;
    #pragma unroll
    for (int p = 0; p < NPART; ++p) {
        f16x4 t = *reinterpret_cast<const f16x4*>(P + (size_t)p * pstride + off);
        a0 += (float)t.x; a1 += (float)t.y; a2 += (float)t.z; a3 += (float)t.w;
    }
    if (RELUB) {
        float4 bb = *reinterpret_cast<const float4*>(bias2 + tid * 4);
        a0 = fmaxf(a0 + bb.x, 0.0f); a1 = fmaxf(a1 + bb.y, 0.0f);
        a2 = fmaxf(a2 + bb.z, 0.0f); a3 = fmaxf(a3 + bb.w, 0.0f);
    }
    float vals[4];
    if (BASEBF16) {
        ushort4 bs = *reinterpret_cast<const ushort4*>((const u16*)basev + off);
        vals[0] = a0 + b2f(bs.x); vals[1] = a1 + b2f(bs.y);
        vals[2] = a2 + b2f(bs.z); vals[3] = a3 + b2f(bs.w);
    } else {
        float4 bs = *reinterpret_cast<const float4*>((const float*)basev + off);
        vals[0] = a0 + bs.x; vals[1] = a1 + bs.y; vals[2] = a2 + bs.z; vals[3] = a3 + bs.w;
    }

    float s = vals[0] + vals[1] + vals[2] + vals[3];
    red[tid] = s; __syncthreads();
    for (int st = 128; st > 0; st >>= 1) { if (tid < st) red[tid] += red[tid + st]; __syncthreads(); }
    float mu = red[0] * (1.0f / DMODEL);
    __syncthreads();

    float vs = 0.0f;
    #pragma unroll
    for (int i = 0; i < 4; ++i) { float d = vals[i] - mu; vs += d * d; }
    red[tid] = vs; __syncthreads();
    for (int st = 128; st > 0; st >>= 1) { if (tid < st) red[tid] += red[tid + st]; __syncthreads(); }
    float rstd = rsqrtf(red[0] * (1.0f / DMODEL) + LNEPS);

    float4 gv = *reinterpret_cast<const float4*>(g + tid * 4);
    float4 bv = *reinterpret_cast<const float4*>(b + tid * 4);
    float gs[4] = {gv.x, gv.y, gv.z, gv.w};
    float bsc[4] = {bv.x, bv.y, bv.z, bv.w};
    #pragma unroll
    for (int i = 0; i < 4; ++i) {
        float r = (vals[i] - mu) * rstd * gs[i] + bsc[i];
        if (OUTF) out[off + i] = r;
        if (DUAL) outb[off + i] = f2b(r);
    }
}

// ---------------- launch ----------------
extern "C" void kernel_launch(void* const* d_in, const int* in_sizes, int n_in,
                              void* d_out, int out_size, void* d_ws, size_t ws_size,
                              hipStream_t stream)
{
    const float* x    = (const float*)d_in[0];
    const float* wq   = (const float*)d_in[1];
    const float* wk   = (const float*)d_in[2];
    const float* wv   = (const float*)d_in[3];
    const float* wo   = (const float*)d_in[4];
    const float* ln1g = (const float*)d_in[5];
    const float* ln1b = (const float*)d_in[6];
    const float* w1   = (const float*)d_in[7];
    const float* b1   = (const float*)d_in[8];
    const float* w2   = (const float*)d_in[9];
    const float* b2   = (const float*)d_in[10];
    const float* ln2g = (const float*)d_in[11];
    const float* ln2b = (const float*)d_in[12];
    float* out = (float*)d_out;

    // 64 MB workspace (liveness-checked):
    //  [0,8)   w2T (prep -> ffn2)          [8,16)  w1T (prep -> ffn1)
    //  [16,18) woT (prep -> oproj)         [18,24) wqkvT (prep -> qkv)
    //  [24,28) xb (prep -> qkv); then ff1b [24,40) (ffn1 -> ffn2)
    //  [28,40) qkvb (qkv -> flash)         [40,44) concatb (flash -> oproj)
    //  [44,60) Ph/Fh fp16 x4 partials      [60,64) h1b (LN1 -> ffn1, LN2 base)
    char* ws = (char*)d_ws;
    const size_t MB = 1024 * 1024;
    u16* w2T     = (u16*)(ws + 0 * MB);
    u16* w1T     = (u16*)(ws + 8 * MB);
    u16* woT     = (u16*)(ws + 16 * MB);
    u16* wqkvT   = (u16*)(ws + 18 * MB);
    u16* xb      = (u16*)(ws + 24 * MB);
    u16* ff1b    = (u16*)(ws + 24 * MB);
    u16* qkvb    = (u16*)(ws + 28 * MB);
    u16* concatb = (u16*)(ws + 40 * MB);
    f16* Ph      = (f16*)(ws + 44 * MB);
    f16* Fh      = (f16*)(ws + 44 * MB);
    u16* h1b     = (u16*)(ws + 60 * MB);

    const size_t PSTRIDE = (size_t)NTOK * DMODEL;

    dim3 blk(256);

    prep_all<<<dim3(13312), blk, 0, stream>>>(x, wq, wk, wv, wo, w1, w2,
                                              xb, wqkvT, woT, w1T, w2T);

    mfma_gemm<0,0,0,1,1><<<dim3(24, 16), blk, 0, stream>>>(
        xb, DMODEL, wqkvT, DMODEL, qkvb, 3 * DMODEL, DMODEL, nullptr, nullptr, 0, 0);
    flash_attn_mfma<<<dim3(512), dim3(512), 0, stream>>>(qkvb, concatb);
    mfma_gemm<0,0,0,0,4><<<dim3(8, 16, 4), blk, 0, stream>>>(
        concatb, DMODEL, woT, DMODEL, Ph, DMODEL, 256, nullptr, nullptr, 0, PSTRIDE);
    ln_fuse<4,0,0,1,0><<<dim3(NTOK), blk, 0, stream>>>(
        Ph, PSTRIDE, x, nullptr, ln1g, ln1b, nullptr, h1b);
    mfma_gemm<1,1,0,1,1><<<dim3(32, 16), blk, 0, stream>>>(
        h1b, DMODEL, w1T, DMODEL, ff1b, DFF, DMODEL, b1, nullptr, 0, 0);
    mfma_gemm<0,0,0,0,4><<<dim3(8, 16, 4), blk, 0, stream>>>(
        ff1b, DFF, w2T, DFF, Fh, DMODEL, 1024, nullptr, nullptr, 0, PSTRIDE);
    ln_fuse<4,1,1,0,1><<<dim3(NTOK), blk, 0, stream>>>(
        Fh, PSTRIDE, h1b, b2, ln2g, ln2b, out, nullptr);
}

// Round 16
// 151.896 us; speedup vs baseline: 1.3857x; 1.0686x over previous
//
#include <hip/hip_runtime.h>
#include <math.h>

// TransformerBlock N=2048, D=1024, H=16, DK=DV=64, FF=4096.
// Round 16: GEMM BK 32->64 via TWO 32-k panels per buffer (same 64B-row
// LDS layout per panel -> no bank-conflict change, no swizzle needed;
// 8 global_load_lds per wave per step). Barrier/vmcnt-drain count halves
// (32 MFMA per barrier). LDS 32->64KB = 2 blocks/CU (equals actual
// co-residency of our 384-512-block grids). Flash/LN/prep = R15 (best).

#define NTOK   2048
#define DMODEL 1024
#define NHEAD  16
#define DHEAD  64
#define DFF    4096
#define LNEPS  1e-5f

typedef unsigned int   u32;
typedef unsigned short u16;
typedef _Float16       f16;
typedef __attribute__((ext_vector_type(8))) short short8;
typedef __attribute__((ext_vector_type(4))) float f32x4;
typedef __attribute__((ext_vector_type(4))) _Float16 f16x4;

__device__ __forceinline__ u16 f2b(float f) {
    u32 b = __float_as_uint(f);
    b += 0x7FFFu + ((b >> 16) & 1u);   // RNE
    return (u16)(b >> 16);
}
__device__ __forceinline__ float b2f(u16 v) {
    return __uint_as_float((u32)v << 16);
}

#define AS1(p) ((const __attribute__((address_space(1))) u32*)(p))
#define AS3(p) ((__attribute__((address_space(3))) u32*)(p))

// ------- bf16 MFMA GEMM, 128x128 tile, BK=64 (2x 32-k panels), dbuf -------
template<int RELU, int BIAS, int RESID, int OUT_BF16, int SPLITK>
__global__ __launch_bounds__(256) void mfma_gemm(
    const u16* __restrict__ A, int lda,
    const u16* __restrict__ Bt, int ldbt,
    void* __restrict__ Cp, int ldc, int Kc,
    const float* __restrict__ bias,
    const float* __restrict__ resid, int ldr,
    size_t pstride)
{
    __shared__ u16 As[2][2][128 * 32];   // [dbuf][panel][row*32+k], 32KB
    __shared__ u16 Bs[2][2][128 * 32];   // 32KB

    const int tid = threadIdx.x;
    const int l = tid & 63, w = tid >> 6;
    const int row0 = blockIdx.y * 128, col0 = blockIdx.x * 128;
    const int kbase = (SPLITK > 1) ? blockIdx.z * Kc : 0;

    f32x4 acc[4][4];
    #pragma unroll
    for (int m = 0; m < 4; ++m)
        #pragma unroll
        for (int n = 0; n < 4; ++n)
            acc[m][n] = (f32x4){0.f, 0.f, 0.f, 0.f};

    const int srow = w * 32 + (l >> 2);
    const int skk  = (l & 3) * 8;
    const u16* Ag = A  + (size_t)(row0 + srow) * lda  + kbase + skk;
    const u16* Bg = Bt + (size_t)(col0 + srow) * ldbt + kbase + skk;

    const int fr  = l & 15;
    const int fk  = (l >> 4) * 8;
    const int ar0 = (w >> 1) * 64;
    const int bc0 = (w & 1) * 64;

    auto STAGE = [&](int buf, int k0) {
        char* A0 = (char*)&As[buf][0][0] + w * 2048;
        char* A1 = (char*)&As[buf][1][0] + w * 2048;
        char* B0 = (char*)&Bs[buf][0][0] + w * 2048;
        char* B1 = (char*)&Bs[buf][1][0] + w * 2048;
        __builtin_amdgcn_global_load_lds(AS1(Ag + k0),                          AS3(A0),        16, 0, 0);
        __builtin_amdgcn_global_load_lds(AS1(Ag + k0 + (size_t)16 * lda),       AS3(A0 + 1024), 16, 0, 0);
        __builtin_amdgcn_global_load_lds(AS1(Ag + k0 + 32),                     AS3(A1),        16, 0, 0);
        __builtin_amdgcn_global_load_lds(AS1(Ag + k0 + 32 + (size_t)16 * lda),  AS3(A1 + 1024), 16, 0, 0);
        __builtin_amdgcn_global_load_lds(AS1(Bg + k0),                          AS3(B0),        16, 0, 0);
        __builtin_amdgcn_global_load_lds(AS1(Bg + k0 + (size_t)16 * ldbt),      AS3(B0 + 1024), 16, 0, 0);
        __builtin_amdgcn_global_load_lds(AS1(Bg + k0 + 32),                     AS3(B1),        16, 0, 0);
        __builtin_amdgcn_global_load_lds(AS1(Bg + k0 + 32 + (size_t)16 * ldbt), AS3(B1 + 1024), 16, 0, 0);
    };

    STAGE(0, 0);
    int cur = 0;
    for (int k0 = 0; k0 < Kc; k0 += 64) {
        __syncthreads();                          // drains vmcnt: buf[cur] ready
        if (k0 + 64 < Kc) STAGE(cur ^ 1, k0 + 64);

        #pragma unroll
        for (int p = 0; p < 2; ++p) {             // two 32-k panels
            short8 af[4], bfr[4];
            #pragma unroll
            for (int m = 0; m < 4; ++m)
                af[m] = *reinterpret_cast<const short8*>(&As[cur][p][(ar0 + m * 16 + fr) * 32 + fk]);
            #pragma unroll
            for (int n = 0; n < 4; ++n)
                bfr[n] = *reinterpret_cast<const short8*>(&Bs[cur][p][(bc0 + n * 16 + fr) * 32 + fk]);
            #pragma unroll
            for (int m = 0; m < 4; ++m)
                #pragma unroll
                for (int n = 0; n < 4; ++n)
                    acc[m][n] = __builtin_amdgcn_mfma_f32_16x16x32_bf16(af[m], bfr[n], acc[m][n], 0, 0, 0);
        }
        cur ^= 1;
    }

    if (SPLITK > 1) {
        f16* Pp = (f16*)Cp + blockIdx.z * pstride;
        #pragma unroll
        for (int m = 0; m < 4; ++m)
            #pragma unroll
            for (int n = 0; n < 4; ++n)
                #pragma unroll
                for (int r = 0; r < 4; ++r) {
                    int row = row0 + ar0 + m * 16 + (l >> 4) * 4 + r;
                    int col = col0 + bc0 + n * 16 + (l & 15);
                    Pp[(size_t)row * ldc + col] = (f16)acc[m][n][r];
                }
        return;
    }

    #pragma unroll
    for (int m = 0; m < 4; ++m) {
        #pragma unroll
        for (int n = 0; n < 4; ++n) {
            #pragma unroll
            for (int r = 0; r < 4; ++r) {
                int row = row0 + ar0 + m * 16 + (l >> 4) * 4 + r;
                int col = col0 + bc0 + n * 16 + (l & 15);
                float val = acc[m][n][r];
                if (BIAS)  val += bias[col];
                if (RESID) val += resid[(size_t)row * ldr + col];
                if (RELU)  val = fmaxf(val, 0.0f);
                if (OUT_BF16) ((u16*)Cp)[(size_t)row * ldc + col] = f2b(val);
                else          ((float*)Cp)[(size_t)row * ldc + col] = val;
            }
        }
    }
}

// ---------------- fused prep: x cast + all weight transposes ----------------
__device__ __forceinline__ void transpose_tile32(
    const float* __restrict__ in, int ldin,
    u16* __restrict__ out, int ldout, int r0, int c0)
{
    __shared__ float tile[32][33];
    int tx = threadIdx.x & 31, ty = threadIdx.x >> 5;
    #pragma unroll
    for (int i = 0; i < 4; ++i) {
        int r = ty + i * 8;
        tile[r][tx] = in[(size_t)(r0 + r) * ldin + c0 + tx];
    }
    __syncthreads();
    #pragma unroll
    for (int i = 0; i < 4; ++i) {
        int rr = ty + i * 8;
        out[(size_t)(c0 + rr) * ldout + r0 + tx] = f2b(tile[tx][rr]);
    }
}

__global__ __launch_bounds__(256) void prep_all(
    const float* __restrict__ x,
    const float* __restrict__ wq, const float* __restrict__ wk, const float* __restrict__ wv,
    const float* __restrict__ wo, const float* __restrict__ w1, const float* __restrict__ w2,
    u16* __restrict__ xb, u16* __restrict__ wqkvT, u16* __restrict__ woT,
    u16* __restrict__ w1T, u16* __restrict__ w2T)
{
    int b = blockIdx.x;
    if (b < 1024) {
        int i = (b * 256 + threadIdx.x) * 8;
        float4 v0 = *reinterpret_cast<const float4*>(x + i);
        float4 v1 = *reinterpret_cast<const float4*>(x + i + 4);
        ushort4 o0, o1;
        o0.x = f2b(v0.x); o0.y = f2b(v0.y); o0.z = f2b(v0.z); o0.w = f2b(v0.w);
        o1.x = f2b(v1.x); o1.y = f2b(v1.y); o1.z = f2b(v1.z); o1.w = f2b(v1.w);
        *reinterpret_cast<ushort4*>(xb + i)     = o0;
        *reinterpret_cast<ushort4*>(xb + i + 4) = o1;
    } else if (b < 4096) {
        int u = b - 1024;
        int z = u >> 6, t = u & 63;
        int p = z >> 4, hh = z & 15;
        const float* in = (p == 0 ? wq : p == 1 ? wk : wv) + (size_t)hh * DMODEL * DHEAD;
        u16* out = wqkvT + (size_t)(p * 1024 + hh * 64) * DMODEL;
        transpose_tile32(in, DHEAD, out, DMODEL, (t >> 1) * 32, (t & 1) * 32);
    } else if (b < 5120) {
        int u = b - 4096;
        transpose_tile32(wo, DMODEL, woT, DMODEL, (u >> 5) * 32, (u & 31) * 32);
    } else if (b < 9216) {
        int u = b - 5120;
        transpose_tile32(w1, DFF, w1T, DMODEL, (u >> 7) * 32, (u & 127) * 32);
    } else {
        int u = b - 9216;
        transpose_tile32(w2, DMODEL, w2T, DFF, (u >> 5) * 32, (u & 31) * 32);
    }
}

// ---------------- 8-wave split-KV swapped-operand flash attention ----------
// R15/R13 structure (best verified). NO min-waves clause (needs ~60 VGPR).
__global__ __launch_bounds__(512) void flash_attn_mfma(
    const u16* __restrict__ qkvb, u16* __restrict__ concatb)
{
    const int bid = blockIdx.x;
    const int lo = bid & 255;
    int it = lo >> 3;
    int h  = lo & 7;
    if (bid >= 256) { it = 31 - it; h += 8; }

    const u16* qh = qkvb + h * DHEAD;
    const u16* kh = qkvb + DMODEL + h * DHEAD;
    const u16* vh = qkvb + 2 * DMODEL + h * DHEAD;
    const int LDQ = 3 * DMODEL;

    const float SC2  = 0.18033688f;    // 0.125 * log2(e)
    const float THR2 = 11.541560f;     // 8 * log2(e)

    __shared__ u16 Ks[4][64][72];
    __shared__ u16 Vt[4][64][72];

    const int tid = threadIdx.x;
    const int l = tid & 63, w = tid >> 6;
    const int grp = w >> 2, wq = w & 3;
    const int fr = l & 15, fg = l >> 4;

    short8 qf[2];
    {
        const u16* qp = qh + (size_t)(it * 64 + wq * 16 + fr) * LDQ + fg * 8;
        qf[0] = *reinterpret_cast<const short8*>(qp);
        qf[1] = *reinterpret_cast<const short8*>(qp + 32);
    }

    const int kr  = tid >> 1;
    const int kb  = kr >> 6, krl = kr & 63;
    const int kc  = (tid & 1) * 32;
    const int vp  = tid >> 2;
    const int vb  = vp >> 5, vpl = vp & 31;
    const int vc  = (tid & 3) * 16;

    short8 kf[4], vf0[2], vf1[2];
    auto PREFETCH = [&](int s) {
        const u16* kg = kh + (size_t)(s * 256 + kr) * LDQ + kc;
        kf[0] = *reinterpret_cast<const short8*>(kg);
        kf[1] = *reinterpret_cast<const short8*>(kg + 8);
        kf[2] = *reinterpret_cast<const short8*>(kg + 16);
        kf[3] = *reinterpret_cast<const short8*>(kg + 24);
        const u16* vg = vh + (size_t)(s * 256 + 2 * vp) * LDQ + vc;
        vf0[0] = *reinterpret_cast<const short8*>(vg);
        vf0[1] = *reinterpret_cast<const short8*>(vg + 8);
        vf1[0] = *reinterpret_cast<const short8*>(vg + LDQ);
        vf1[1] = *reinterpret_cast<const short8*>(vg + LDQ + 8);
    };

    f32x4 o[4];
    #pragma unroll
    for (int n = 0; n < 4; ++n) o[n] = (f32x4){0.f, 0.f, 0.f, 0.f};
    float m_run = -INFINITY, l_run = 0.0f;     // base-2 log domain

    const int sA = fr + 16 * ((2 * fg) & 3);
    const int sB = sA + 16;
    const bool hi = (fg >= 2);

    char* VtSb = (char*)&Vt[vb][0][0];

    const int niter = (it >> 2) + 1;
    PREFETCH(0);

    for (int s = 0; s < niter; ++s) {
        __syncthreads();
        *reinterpret_cast<short8*>(&Ks[kb][krl][kc +  0]) = kf[0];
        *reinterpret_cast<short8*>(&Ks[kb][krl][kc +  8]) = kf[1];
        *reinterpret_cast<short8*>(&Ks[kb][krl][kc + 16]) = kf[2];
        *reinterpret_cast<short8*>(&Ks[kb][krl][kc + 24]) = kf[3];
        #pragma unroll
        for (int c2 = 0; c2 < 2; ++c2) {
            #pragma unroll
            for (int i = 0; i < 8; ++i) {
                u32 word = (u32)(u16)vf0[c2][i] | ((u32)(u16)vf1[c2][i] << 16);
                int dv = vc + c2 * 8 + i;
                int off = 144 * dv + 16 * ((vpl >> 2) ^ ((dv >> 3) & 7)) + 4 * (vpl & 3);
                *reinterpret_cast<u32*>(VtSb + off) = word;
            }
        }
        if (s + 1 < niter) PREFETCH(s + 1);
        __syncthreads();

        #pragma unroll
        for (int t = 0; t < 2; ++t) {
            const int jt = 4 * s + 2 * grp + t;
            if (jt > it) continue;
            const int buf = 2 * grp + t;
            const u16 (*KsG)[72] = Ks[buf];
            char* VtG = (char*)&Vt[buf][0][0];

            f32x4 s_[4];
            #pragma unroll
            for (int n = 0; n < 4; ++n) s_[n] = (f32x4){0.f, 0.f, 0.f, 0.f};
            __builtin_amdgcn_s_setprio(1);
            #pragma unroll
            for (int n = 0; n < 4; ++n) {
                #pragma unroll
                for (int ks = 0; ks < 2; ++ks) {
                    short8 kfrag = *reinterpret_cast<const short8*>(&KsG[n * 16 + fr][ks * 32 + fg * 8]);
                    s_[n] = __builtin_amdgcn_mfma_f32_16x16x32_bf16(kfrag, qf[ks], s_[n], 0, 0, 0);
                }
            }
            __builtin_amdgcn_s_setprio(0);

            const bool diag = (jt == it);
            const int qrow_t = wq * 16 + fr;
            float sv[4][4];
            float pm = -INFINITY;
            #pragma unroll
            for (int n = 0; n < 4; ++n)
                #pragma unroll
                for (int r = 0; r < 4; ++r) {
                    float v = s_[n][r] * SC2;
                    if (diag && (n * 16 + fg * 4 + r) > qrow_t) v = -INFINITY;
                    sv[n][r] = v;
                    pm = fmaxf(pm, v);
                }
            pm = fmaxf(pm, __shfl_xor(pm, 16));
            pm = fmaxf(pm, __shfl_xor(pm, 32));
            if (!__all(pm <= m_run + THR2)) {
                float mnew = fmaxf(m_run, pm);
                float corr = exp2f(m_run - mnew);
                l_run *= corr;
                #pragma unroll
                for (int n = 0; n < 4; ++n) {
                    o[n][0] *= corr; o[n][1] *= corr; o[n][2] *= corr; o[n][3] *= corr;
                }
                m_run = mnew;
            }
            float rs = 0.0f;
            float pp[4][4];
            #pragma unroll
            for (int n = 0; n < 4; ++n)
                #pragma unroll
                for (int r = 0; r < 4; ++r) {
                    float pv = exp2f(sv[n][r] - m_run);
                    pp[n][r] = pv;
                    rs += pv;
                }
            rs += __shfl_xor(rs, 16);
            rs += __shfl_xor(rs, 32);
            l_run += rs;

            u32 pk[4][2];
            #pragma unroll
            for (int n = 0; n < 4; ++n) {
                pk[n][0] = (__float_as_uint(pp[n][0]) >> 16) | (__float_as_uint(pp[n][1]) & 0xFFFF0000u);
                pk[n][1] = (__float_as_uint(pp[n][2]) >> 16) | (__float_as_uint(pp[n][3]) & 0xFFFF0000u);
            }

            __builtin_amdgcn_s_setprio(1);
            #pragma unroll
            for (int ks = 0; ks < 2; ++ks) {
                u32 a0 = __shfl(pk[2 * ks][0], sA);
                u32 a1 = __shfl(pk[2 * ks][1], sA);
                u32 a2 = __shfl(pk[2 * ks][0], sB);
                u32 a3 = __shfl(pk[2 * ks][1], sB);
                u32 b0 = __shfl(pk[2 * ks + 1][0], sA);
                u32 b1 = __shfl(pk[2 * ks + 1][1], sA);
                u32 b2 = __shfl(pk[2 * ks + 1][0], sB);
                u32 b3 = __shfl(pk[2 * ks + 1][1], sB);
                union { u32 u[4]; short8 s8; } pb;
                pb.u[0] = hi ? b0 : a0;
                pb.u[1] = hi ? b1 : a1;
                pb.u[2] = hi ? b2 : a2;
                pb.u[3] = hi ? b3 : a3;
                #pragma unroll
                for (int n = 0; n < 4; ++n) {
                    int dv = n * 16 + fr;
                    const short8* vfrag = reinterpret_cast<const short8*>(
                        VtG + 144 * dv + 16 * ((ks * 4 + fg) ^ ((dv >> 3) & 7)));
                    o[n] = __builtin_amdgcn_mfma_f32_16x16x32_bf16(*vfrag, pb.s8, o[n], 0, 0, 0);
                }
            }
            __builtin_amdgcn_s_setprio(0);
        }
    }

    // ---- merge group B partials into group A via LDS (overlay on Ks) ----
    __syncthreads();
    float* mrg = reinterpret_cast<float*>(&Ks[0][0][0]);
    const int slot = (wq * 64 + l) * 18;
    if (grp == 1) {
        #pragma unroll
        for (int n = 0; n < 4; ++n)
            #pragma unroll
            for (int r = 0; r < 4; ++r)
                mrg[slot + n * 4 + r] = o[n][r];
        mrg[slot + 16] = m_run;
        mrg[slot + 17] = l_run;
    }
    __syncthreads();
    if (grp == 0) {
        float mB = mrg[slot + 16], lB = mrg[slot + 17];
        float mstar = fmaxf(m_run, mB);
        float cA = exp2f(m_run - mstar);
        float cB = exp2f(mB - mstar);
        float inv = 1.0f / (l_run * cA + lB * cB);
        int qrow = it * 64 + wq * 16 + fr;
        #pragma unroll
        for (int n = 0; n < 4; ++n)
            #pragma unroll
            for (int r = 0; r < 4; ++r) {
                float val = (o[n][r] * cA + mrg[slot + n * 4 + r] * cB) * inv;
                concatb[(size_t)qrow * DMODEL + h * DHEAD + n * 16 + fg * 4 + r] = f2b(val);
            }
    }
}

// ---------------- fused fp16-partial-reduce + LayerNorm ----------------
template<int NPART, int RELUB, int OUTF, int DUAL, int BASEBF16>
__global__ __launch_bounds__(256) void ln_fuse(
    const f16* __restrict__ P, size_t pstride,
    const void* __restrict__ basev,
    const float* __restrict__ bias2,
    const float* __restrict__ g, const float* __restrict__ b,
    float* __restrict__ out, u16* __restrict__ outb)
{
    int row = blockIdx.x, tid = threadIdx.x;
    __shared__ float red[256];
    size_t off = (size_t)row * DMODEL + tid * 4;

    float a0 = 0.f, a1 = 0.f, a2 = 0.f, a3 = 0.f;
    #pragma unroll
    for (int p = 0; p < NPART; ++p) {
        f16x4 t = *reinterpret_cast<const f16x4*>(P + (size_t)p * pstride + off);
        a0 += (float)t.x; a1 += (float)t.y; a2 += (float)t.z; a3 += (float)t.w;
    }
    if (RELUB) {
        float4 bb = *reinterpret_cast<const float4*>(bias2 + tid * 4);
        a0 = fmaxf(a0 + bb.x, 0.0f); a1 = fmaxf(a1 + bb.y, 0.0f);
        a2 = fmaxf(a2 + bb.z, 0.0f); a3 = fmaxf(a3 + bb.w, 0.0f);
    }
    float vals[4];
    if (BASEBF16) {
        ushort4 bs = *reinterpret_cast<const ushort4*>((const u16*)basev + off);
        vals[0] = a0 + b2f(bs.x); vals[1] = a1 + b2f(bs.y);
        vals[2] = a2 + b2f(bs.z); vals[3] = a3 + b2f(bs.w);
    } else {
        float4 bs = *reinterpret_cast<const float4*>((const float*)basev + off);
        vals[0] = a0 + bs.x; vals[1] = a1 + bs.y; vals[2] = a2 + bs.z; vals[3] = a3 + bs.w;
    }

    float s = vals[0] + vals[1] + vals[2] + vals[3];
    red[tid] = s; __syncthreads();
    for (int st = 128; st > 0; st >>= 1) { if (tid < st) red[tid] += red[tid + st]; __syncthreads(); }
    float mu = red[0] * (1.0f / DMODEL);
    __syncthreads();

    float vs = 0.0f;
    #pragma unroll
    for (int i = 0; i < 4; ++i) { float d = vals[i] - mu; vs += d * d; }
    red[tid] = vs; __syncthreads();
    for (int st = 128; st > 0; st >>= 1) { if (tid < st) red[tid] += red[tid + st]; __syncthreads(); }
    float rstd = rsqrtf(red[0] * (1.0f / DMODEL) + LNEPS);

    float4 gv = *reinterpret_cast<const float4*>(g + tid * 4);
    float4 bv = *reinterpret_cast<const float4*>(b + tid * 4);
    float gs[4] = {gv.x, gv.y, gv.z, gv.w};
    float bsc[4] = {bv.x, bv.y, bv.z, bv.w};
    #pragma unroll
    for (int i = 0; i < 4; ++i) {
        float r = (vals[i] - mu) * rstd * gs[i] + bsc[i];
        if (OUTF) out[off + i] = r;
        if (DUAL) outb[off + i] = f2b(r);
    }
}

// ---------------- launch ----------------
extern "C" void kernel_launch(void* const* d_in, const int* in_sizes, int n_in,
                              void* d_out, int out_size, void* d_ws, size_t ws_size,
                              hipStream_t stream)
{
    const float* x    = (const float*)d_in[0];
    const float* wq   = (const float*)d_in[1];
    const float* wk   = (const float*)d_in[2];
    const float* wv   = (const float*)d_in[3];
    const float* wo   = (const float*)d_in[4];
    const float* ln1g = (const float*)d_in[5];
    const float* ln1b = (const float*)d_in[6];
    const float* w1   = (const float*)d_in[7];
    const float* b1   = (const float*)d_in[8];
    const float* w2   = (const float*)d_in[9];
    const float* b2   = (const float*)d_in[10];
    const float* ln2g = (const float*)d_in[11];
    const float* ln2b = (const float*)d_in[12];
    float* out = (float*)d_out;

    // 64 MB workspace (liveness-checked):
    //  [0,8)   w2T (prep -> ffn2)          [8,16)  w1T (prep -> ffn1)
    //  [16,18) woT (prep -> oproj)         [18,24) wqkvT (prep -> qkv)
    //  [24,28) xb (prep -> qkv); then ff1b [24,40) (ffn1 -> ffn2)
    //  [28,40) qkvb (qkv -> flash)         [40,44) concatb (flash -> oproj)
    //  [44,60) Ph/Fh fp16 x4 partials      [60,64) h1b (LN1 -> ffn1, LN2 base)
    char* ws = (char*)d_ws;
    const size_t MB = 1024 * 1024;
    u16* w2T     = (u16*)(ws + 0 * MB);
    u16* w1T     = (u16*)(ws + 8 * MB);
    u16* woT     = (u16*)(ws + 16 * MB);
    u16* wqkvT   = (u16*)(ws + 18 * MB);
    u16* xb      = (u16*)(ws + 24 * MB);
    u16* ff1b    = (u16*)(ws + 24 * MB);
    u16* qkvb    = (u16*)(ws + 28 * MB);
    u16* concatb = (u16*)(ws + 40 * MB);
    f16* Ph      = (f16*)(ws + 44 * MB);
    f16* Fh      = (f16*)(ws + 44 * MB);
    u16* h1b     = (u16*)(ws + 60 * MB);

    const size_t PSTRIDE = (size_t)NTOK * DMODEL;

    dim3 blk(256);

    prep_all<<<dim3(13312), blk, 0, stream>>>(x, wq, wk, wv, wo, w1, w2,
                                              xb, wqkvT, woT, w1T, w2T);

    mfma_gemm<0,0,0,1,1><<<dim3(24, 16), blk, 0, stream>>>(
        xb, DMODEL, wqkvT, DMODEL, qkvb, 3 * DMODEL, DMODEL, nullptr, nullptr, 0, 0);
    flash_attn_mfma<<<dim3(512), dim3(512), 0, stream>>>(qkvb, concatb);
    mfma_gemm<0,0,0,0,4><<<dim3(8, 16, 4), blk, 0, stream>>>(
        concatb, DMODEL, woT, DMODEL, Ph, DMODEL, 256, nullptr, nullptr, 0, PSTRIDE);
    ln_fuse<4,0,0,1,0><<<dim3(NTOK), blk, 0, stream>>>(
        Ph, PSTRIDE, x, nullptr, ln1g, ln1b, nullptr, h1b);
    mfma_gemm<1,1,0,1,1><<<dim3(32, 16), blk, 0, stream>>>(
        h1b, DMODEL, w1T, DMODEL, ff1b, DFF, DMODEL, b1, nullptr, 0, 0);
    mfma_gemm<0,0,0,0,4><<<dim3(8, 16, 4), blk, 0, stream>>>(
        ff1b, DFF, w2T, DFF, Fh, DMODEL, 1024, nullptr, nullptr, 0, PSTRIDE);
    ln_fuse<4,1,1,0,1><<<dim3(NTOK), blk, 0, stream>>>(
        Fh, PSTRIDE, h1b, b2, ln2g, ln2b, out, nullptr);
}

// Round 17
// 149.335 us; speedup vs baseline: 1.4095x; 1.0172x over previous
//
#include <hip/hip_runtime.h>
#include <math.h>

// TransformerBlock N=2048, D=1024, H=16, DK=DV=64, FF=4096.
// Round 17: R14's 16-wave flash (4 q-waves x 4 kv-groups, serial chain
// 16->8 tiles) with PLAIN __launch_bounds__(1024) — R14's regression was
// solely the ",8" min-waves clause forcing VGPR 60->32 (full spill).
// Body needs ~52 VGPR; plain bound caps at 128. GEMM = R16 (BK=64 panels).

#define NTOK   2048
#define DMODEL 1024
#define NHEAD  16
#define DHEAD  64
#define DFF    4096
#define LNEPS  1e-5f

typedef unsigned int   u32;
typedef unsigned short u16;
typedef _Float16       f16;
typedef __attribute__((ext_vector_type(8))) short short8;
typedef __attribute__((ext_vector_type(4))) float f32x4;
typedef __attribute__((ext_vector_type(4))) _Float16 f16x4;

__device__ __forceinline__ u16 f2b(float f) {
    u32 b = __float_as_uint(f);
    b += 0x7FFFu + ((b >> 16) & 1u);   // RNE
    return (u16)(b >> 16);
}
__device__ __forceinline__ float b2f(u16 v) {
    return __uint_as_float((u32)v << 16);
}

#define AS1(p) ((const __attribute__((address_space(1))) u32*)(p))
#define AS3(p) ((__attribute__((address_space(3))) u32*)(p))

// ------- bf16 MFMA GEMM, 128x128 tile, BK=64 (2x 32-k panels), dbuf -------
template<int RELU, int BIAS, int RESID, int OUT_BF16, int SPLITK>
__global__ __launch_bounds__(256) void mfma_gemm(
    const u16* __restrict__ A, int lda,
    const u16* __restrict__ Bt, int ldbt,
    void* __restrict__ Cp, int ldc, int Kc,
    const float* __restrict__ bias,
    const float* __restrict__ resid, int ldr,
    size_t pstride)
{
    __shared__ u16 As[2][2][128 * 32];
    __shared__ u16 Bs[2][2][128 * 32];

    const int tid = threadIdx.x;
    const int l = tid & 63, w = tid >> 6;
    const int row0 = blockIdx.y * 128, col0 = blockIdx.x * 128;
    const int kbase = (SPLITK > 1) ? blockIdx.z * Kc : 0;

    f32x4 acc[4][4];
    #pragma unroll
    for (int m = 0; m < 4; ++m)
        #pragma unroll
        for (int n = 0; n < 4; ++n)
            acc[m][n] = (f32x4){0.f, 0.f, 0.f, 0.f};

    const int srow = w * 32 + (l >> 2);
    const int skk  = (l & 3) * 8;
    const u16* Ag = A  + (size_t)(row0 + srow) * lda  + kbase + skk;
    const u16* Bg = Bt + (size_t)(col0 + srow) * ldbt + kbase + skk;

    const int fr  = l & 15;
    const int fk  = (l >> 4) * 8;
    const int ar0 = (w >> 1) * 64;
    const int bc0 = (w & 1) * 64;

    auto STAGE = [&](int buf, int k0) {
        char* A0 = (char*)&As[buf][0][0] + w * 2048;
        char* A1 = (char*)&As[buf][1][0] + w * 2048;
        char* B0 = (char*)&Bs[buf][0][0] + w * 2048;
        char* B1 = (char*)&Bs[buf][1][0] + w * 2048;
        __builtin_amdgcn_global_load_lds(AS1(Ag + k0),                          AS3(A0),        16, 0, 0);
        __builtin_amdgcn_global_load_lds(AS1(Ag + k0 + (size_t)16 * lda),       AS3(A0 + 1024), 16, 0, 0);
        __builtin_amdgcn_global_load_lds(AS1(Ag + k0 + 32),                     AS3(A1),        16, 0, 0);
        __builtin_amdgcn_global_load_lds(AS1(Ag + k0 + 32 + (size_t)16 * lda),  AS3(A1 + 1024), 16, 0, 0);
        __builtin_amdgcn_global_load_lds(AS1(Bg + k0),                          AS3(B0),        16, 0, 0);
        __builtin_amdgcn_global_load_lds(AS1(Bg + k0 + (size_t)16 * ldbt),      AS3(B0 + 1024), 16, 0, 0);
        __builtin_amdgcn_global_load_lds(AS1(Bg + k0 + 32),                     AS3(B1),        16, 0, 0);
        __builtin_amdgcn_global_load_lds(AS1(Bg + k0 + 32 + (size_t)16 * ldbt), AS3(B1 + 1024), 16, 0, 0);
    };

    STAGE(0, 0);
    int cur = 0;
    for (int k0 = 0; k0 < Kc; k0 += 64) {
        __syncthreads();
        if (k0 + 64 < Kc) STAGE(cur ^ 1, k0 + 64);

        #pragma unroll
        for (int p = 0; p < 2; ++p) {
            short8 af[4], bfr[4];
            #pragma unroll
            for (int m = 0; m < 4; ++m)
                af[m] = *reinterpret_cast<const short8*>(&As[cur][p][(ar0 + m * 16 + fr) * 32 + fk]);
            #pragma unroll
            for (int n = 0; n < 4; ++n)
                bfr[n] = *reinterpret_cast<const short8*>(&Bs[cur][p][(bc0 + n * 16 + fr) * 32 + fk]);
            #pragma unroll
            for (int m = 0; m < 4; ++m)
                #pragma unroll
                for (int n = 0; n < 4; ++n)
                    acc[m][n] = __builtin_amdgcn_mfma_f32_16x16x32_bf16(af[m], bfr[n], acc[m][n], 0, 0, 0);
        }
        cur ^= 1;
    }

    if (SPLITK > 1) {
        f16* Pp = (f16*)Cp + blockIdx.z * pstride;
        #pragma unroll
        for (int m = 0; m < 4; ++m)
            #pragma unroll
            for (int n = 0; n < 4; ++n)
                #pragma unroll
                for (int r = 0; r < 4; ++r) {
                    int row = row0 + ar0 + m * 16 + (l >> 4) * 4 + r;
                    int col = col0 + bc0 + n * 16 + (l & 15);
                    Pp[(size_t)row * ldc + col] = (f16)acc[m][n][r];
                }
        return;
    }

    #pragma unroll
    for (int m = 0; m < 4; ++m) {
        #pragma unroll
        for (int n = 0; n < 4; ++n) {
            #pragma unroll
            for (int r = 0; r < 4; ++r) {
                int row = row0 + ar0 + m * 16 + (l >> 4) * 4 + r;
                int col = col0 + bc0 + n * 16 + (l & 15);
                float val = acc[m][n][r];
                if (BIAS)  val += bias[col];
                if (RESID) val += resid[(size_t)row * ldr + col];
                if (RELU)  val = fmaxf(val, 0.0f);
                if (OUT_BF16) ((u16*)Cp)[(size_t)row * ldc + col] = f2b(val);
                else          ((float*)Cp)[(size_t)row * ldc + col] = val;
            }
        }
    }
}

// ---------------- fused prep: x cast + all weight transposes ----------------
__device__ __forceinline__ void transpose_tile32(
    const float* __restrict__ in, int ldin,
    u16* __restrict__ out, int ldout, int r0, int c0)
{
    __shared__ float tile[32][33];
    int tx = threadIdx.x & 31, ty = threadIdx.x >> 5;
    #pragma unroll
    for (int i = 0; i < 4; ++i) {
        int r = ty + i * 8;
        tile[r][tx] = in[(size_t)(r0 + r) * ldin + c0 + tx];
    }
    __syncthreads();
    #pragma unroll
    for (int i = 0; i < 4; ++i) {
        int rr = ty + i * 8;
        out[(size_t)(c0 + rr) * ldout + r0 + tx] = f2b(tile[tx][rr]);
    }
}

__global__ __launch_bounds__(256) void prep_all(
    const float* __restrict__ x,
    const float* __restrict__ wq, const float* __restrict__ wk, const float* __restrict__ wv,
    const float* __restrict__ wo, const float* __restrict__ w1, const float* __restrict__ w2,
    u16* __restrict__ xb, u16* __restrict__ wqkvT, u16* __restrict__ woT,
    u16* __restrict__ w1T, u16* __restrict__ w2T)
{
    int b = blockIdx.x;
    if (b < 1024) {
        int i = (b * 256 + threadIdx.x) * 8;
        float4 v0 = *reinterpret_cast<const float4*>(x + i);
        float4 v1 = *reinterpret_cast<const float4*>(x + i + 4);
        ushort4 o0, o1;
        o0.x = f2b(v0.x); o0.y = f2b(v0.y); o0.z = f2b(v0.z); o0.w = f2b(v0.w);
        o1.x = f2b(v1.x); o1.y = f2b(v1.y); o1.z = f2b(v1.z); o1.w = f2b(v1.w);
        *reinterpret_cast<ushort4*>(xb + i)     = o0;
        *reinterpret_cast<ushort4*>(xb + i + 4) = o1;
    } else if (b < 4096) {
        int u = b - 1024;
        int z = u >> 6, t = u & 63;
        int p = z >> 4, hh = z & 15;
        const float* in = (p == 0 ? wq : p == 1 ? wk : wv) + (size_t)hh * DMODEL * DHEAD;
        u16* out = wqkvT + (size_t)(p * 1024 + hh * 64) * DMODEL;
        transpose_tile32(in, DHEAD, out, DMODEL, (t >> 1) * 32, (t & 1) * 32);
    } else if (b < 5120) {
        int u = b - 4096;
        transpose_tile32(wo, DMODEL, woT, DMODEL, (u >> 5) * 32, (u & 31) * 32);
    } else if (b < 9216) {
        int u = b - 5120;
        transpose_tile32(w1, DFF, w1T, DMODEL, (u >> 7) * 32, (u & 127) * 32);
    } else {
        int u = b - 9216;
        transpose_tile32(w2, DMODEL, w2T, DFF, (u >> 5) * 32, (u & 31) * 32);
    }
}

// ---------------- 16-wave 4-way-split-KV flash attention ----------
// 512 blocks (pair remap), 1024 threads = 4 q-waves x 4 kv-groups.
// Iteration s stages kv-tiles 4s..4s+3; group g computes tile 4s+g.
// PLAIN launch_bounds(1024): VGPR cap 128, body needs ~52 -> no spill.
__global__ __launch_bounds__(1024) void flash_attn_mfma(
    const u16* __restrict__ qkvb, u16* __restrict__ concatb)
{
    const int bid = blockIdx.x;
    const int lo = bid & 255;
    int it = lo >> 3;
    int h  = lo & 7;
    if (bid >= 256) { it = 31 - it; h += 8; }

    const u16* qh = qkvb + h * DHEAD;
    const u16* kh = qkvb + DMODEL + h * DHEAD;
    const u16* vh = qkvb + 2 * DMODEL + h * DHEAD;
    const int LDQ = 3 * DMODEL;

    const float SC2  = 0.18033688f;    // 0.125 * log2(e)
    const float THR2 = 11.541560f;     // 8 * log2(e)

    __shared__ u16 Ks[4][64][72];
    __shared__ u16 Vt[4][64][72];

    const int tid = threadIdx.x;
    const int l = tid & 63, w = tid >> 6;      // w in 0..15
    const int grp = w >> 2, wq = w & 3;        // 4 kv-groups x 4 q-waves
    const int fr = l & 15, fg = l >> 4;

    short8 qf[2];
    {
        const u16* qp = qh + (size_t)(it * 64 + wq * 16 + fr) * LDQ + fg * 8;
        qf[0] = *reinterpret_cast<const short8*>(qp);
        qf[1] = *reinterpret_cast<const short8*>(qp + 32);
    }

    // staging over 1024 threads: 256 kv rows (4 tiles) per iteration
    const int kr  = tid >> 2;            // 0..255
    const int kb  = kr >> 6, krl = kr & 63;
    const int kc  = (tid & 3) * 16;
    const int vp  = tid >> 3;            // 0..127 row-pairs
    const int vb  = vp >> 5, vpl = vp & 31;
    const int vc  = (tid & 7) * 8;

    short8 kf0, kf1, vf0, vf1;
    auto PREFETCH = [&](int s) {
        const u16* kg = kh + (size_t)(s * 256 + kr) * LDQ + kc;
        kf0 = *reinterpret_cast<const short8*>(kg);
        kf1 = *reinterpret_cast<const short8*>(kg + 8);
        const u16* vg = vh + (size_t)(s * 256 + 2 * vp) * LDQ + vc;
        vf0 = *reinterpret_cast<const short8*>(vg);
        vf1 = *reinterpret_cast<const short8*>(vg + LDQ);
    };

    f32x4 o[4];
    #pragma unroll
    for (int n = 0; n < 4; ++n) o[n] = (f32x4){0.f, 0.f, 0.f, 0.f};
    float m_run = -INFINITY, l_run = 0.0f;     // base-2 log domain

    const int sA = fr + 16 * ((2 * fg) & 3);
    const int sB = sA + 16;
    const bool hi = (fg >= 2);

    char* VtSb = (char*)&Vt[vb][0][0];

    const int niter = (it >> 2) + 1;
    PREFETCH(0);

    for (int s = 0; s < niter; ++s) {
        __syncthreads();
        *reinterpret_cast<short8*>(&Ks[kb][krl][kc])     = kf0;
        *reinterpret_cast<short8*>(&Ks[kb][krl][kc + 8]) = kf1;
        #pragma unroll
        for (int i = 0; i < 8; ++i) {
            u32 word = (u32)(u16)vf0[i] | ((u32)(u16)vf1[i] << 16);
            int dv = vc + i;
            int off = 144 * dv + 16 * ((vpl >> 2) ^ ((dv >> 3) & 7)) + 4 * (vpl & 3);
            *reinterpret_cast<u32*>(VtSb + off) = word;
        }
        if (s + 1 < niter) PREFETCH(s + 1);
        __syncthreads();

        const int jt = 4 * s + grp;
        if (jt > it) continue;
        const u16 (*KsG)[72] = Ks[grp];
        char* VtG = (char*)&Vt[grp][0][0];

        f32x4 s_[4];
        #pragma unroll
        for (int n = 0; n < 4; ++n) s_[n] = (f32x4){0.f, 0.f, 0.f, 0.f};
        __builtin_amdgcn_s_setprio(1);
        #pragma unroll
        for (int n = 0; n < 4; ++n) {
            #pragma unroll
            for (int ks = 0; ks < 2; ++ks) {
                short8 kfrag = *reinterpret_cast<const short8*>(&KsG[n * 16 + fr][ks * 32 + fg * 8]);
                s_[n] = __builtin_amdgcn_mfma_f32_16x16x32_bf16(kfrag, qf[ks], s_[n], 0, 0, 0);
            }
        }
        __builtin_amdgcn_s_setprio(0);

        const bool diag = (jt == it);
        const int qrow_t = wq * 16 + fr;
        float sv[4][4];
        float pm = -INFINITY;
        #pragma unroll
        for (int n = 0; n < 4; ++n)
            #pragma unroll
            for (int r = 0; r < 4; ++r) {
                float v = s_[n][r] * SC2;
                if (diag && (n * 16 + fg * 4 + r) > qrow_t) v = -INFINITY;
                sv[n][r] = v;
                pm = fmaxf(pm, v);
            }
        pm = fmaxf(pm, __shfl_xor(pm, 16));
        pm = fmaxf(pm, __shfl_xor(pm, 32));
        if (!__all(pm <= m_run + THR2)) {
            float mnew = fmaxf(m_run, pm);
            float corr = exp2f(m_run - mnew);
            l_run *= corr;
            #pragma unroll
            for (int n = 0; n < 4; ++n) {
                o[n][0] *= corr; o[n][1] *= corr; o[n][2] *= corr; o[n][3] *= corr;
            }
            m_run = mnew;
        }
        float rs = 0.0f;
        float pp[4][4];
        #pragma unroll
        for (int n = 0; n < 4; ++n)
            #pragma unroll
            for (int r = 0; r < 4; ++r) {
                float pv = exp2f(sv[n][r] - m_run);
                pp[n][r] = pv;
                rs += pv;
            }
        rs += __shfl_xor(rs, 16);
        rs += __shfl_xor(rs, 32);
        l_run += rs;

        u32 pk[4][2];
        #pragma unroll
        for (int n = 0; n < 4; ++n) {
            pk[n][0] = (__float_as_uint(pp[n][0]) >> 16) | (__float_as_uint(pp[n][1]) & 0xFFFF0000u);
            pk[n][1] = (__float_as_uint(pp[n][2]) >> 16) | (__float_as_uint(pp[n][3]) & 0xFFFF0000u);
        }

        __builtin_amdgcn_s_setprio(1);
        #pragma unroll
        for (int ks = 0; ks < 2; ++ks) {
            u32 a0 = __shfl(pk[2 * ks][0], sA);
            u32 a1 = __shfl(pk[2 * ks][1], sA);
            u32 a2 = __shfl(pk[2 * ks][0], sB);
            u32 a3 = __shfl(pk[2 * ks][1], sB);
            u32 b0 = __shfl(pk[2 * ks + 1][0], sA);
            u32 b1 = __shfl(pk[2 * ks + 1][1], sA);
            u32 b2 = __shfl(pk[2 * ks + 1][0], sB);
            u32 b3 = __shfl(pk[2 * ks + 1][1], sB);
            union { u32 u[4]; short8 s8; } pb;
            pb.u[0] = hi ? b0 : a0;
            pb.u[1] = hi ? b1 : a1;
            pb.u[2] = hi ? b2 : a2;
            pb.u[3] = hi ? b3 : a3;
            #pragma unroll
            for (int n = 0; n < 4; ++n) {
                int dv = n * 16 + fr;
                const short8* vfrag = reinterpret_cast<const short8*>(
                    VtG + 144 * dv + 16 * ((ks * 4 + fg) ^ ((dv >> 3) & 7)));
                o[n] = __builtin_amdgcn_mfma_f32_16x16x32_bf16(*vfrag, pb.s8, o[n], 0, 0, 0);
            }
        }
        __builtin_amdgcn_s_setprio(0);
    }

    // ---- 2-round tree merge via LDS (overlay on Ks; fp32; -inf guarded) ----
    float* mrg = reinterpret_cast<float*>(&Ks[0][0][0]);
    const int slotL = (wq * 64 + l) * 18;
    const int slotH = (256 + wq * 64 + l) * 18;

    auto WRITE = [&](int slot) {
        #pragma unroll
        for (int n = 0; n < 4; ++n)
            #pragma unroll
            for (int r = 0; r < 4; ++r)
                mrg[slot + n * 4 + r] = o[n][r];
        mrg[slot + 16] = m_run;
        mrg[slot + 17] = l_run;
    };
    auto MERGE = [&](int slot) {
        float m2 = mrg[slot + 16];
        if (m2 > -INFINITY) {
            float l2 = mrg[slot + 17];
            float mstar = fmaxf(m_run, m2);
            float cA = exp2f(m_run - mstar);
            float cB = exp2f(m2 - mstar);
            #pragma unroll
            for (int n = 0; n < 4; ++n)
                #pragma unroll
                for (int r = 0; r < 4; ++r)
                    o[n][r] = o[n][r] * cA + mrg[slot + n * 4 + r] * cB;
            l_run = l_run * cA + l2 * cB;
            m_run = mstar;
        }
    };

    __syncthreads();
    if (grp == 1) WRITE(slotL);
    if (grp == 3) WRITE(slotH);
    __syncthreads();
    if (grp == 0) MERGE(slotL);
    if (grp == 2) MERGE(slotH);
    __syncthreads();
    if (grp == 2) WRITE(slotL);
    __syncthreads();
    if (grp == 0) {
        MERGE(slotL);
        float inv = 1.0f / l_run;
        int qrow = it * 64 + wq * 16 + fr;
        #pragma unroll
        for (int n = 0; n < 4; ++n)
            #pragma unroll
            for (int r = 0; r < 4; ++r)
                concatb[(size_t)qrow * DMODEL + h * DHEAD + n * 16 + fg * 4 + r] = f2b(o[n][r] * inv);
    }
}

// ---------------- fused fp16-partial-reduce + LayerNorm ----------------
template<int NPART, int RELUB, int OUTF, int DUAL, int BASEBF16>
__global__ __launch_bounds__(256) void ln_fuse(
    const f16* __restrict__ P, size_t pstride,
    const void* __restrict__ basev,
    const float* __restrict__ bias2,
    const float* __restrict__ g, const float* __restrict__ b,
    float* __restrict__ out, u16* __restrict__ outb)
{
    int row = blockIdx.x, tid = threadIdx.x;
    __shared__ float red[256];
    size_t off = (size_t)row * DMODEL + tid * 4;

    float a0 = 0.f, a1 = 0.f, a2 = 0.f, a3 = 0.f;
    #pragma unroll
    for (int p = 0; p < NPART; ++p) {
        f16x4 t = *reinterpret_cast<const f16x4*>(P + (size_t)p * pstride + off);
        a0 += (float)t.x; a1 += (float)t.y; a2 += (float)t.z; a3 += (float)t.w;
    }
    if (RELUB) {
        float4 bb = *reinterpret_cast<const float4*>(bias2 + tid * 4);
        a0 = fmaxf(a0 + bb.x, 0.0f); a1 = fmaxf(a1 + bb.y, 0.0f);
        a2 = fmaxf(a2 + bb.z, 0.0f); a3 = fmaxf(a3 + bb.w, 0.0f);
    }
    float vals[4];
    if (BASEBF16) {
        ushort4 bs = *reinterpret_cast<const ushort4*>((const u16*)basev + off);
        vals[0] = a0 + b2f(bs.x); vals[1] = a1 + b2f(bs.y);
        vals[2] = a2 + b2f(bs.z); vals[3] = a3 + b2f(bs.w);
    } else {
        float4 bs = *reinterpret_cast<const float4*>((const float*)basev + off);
        vals[0] = a0 + bs.x; vals[1] = a1 + bs.y; vals[2] = a2 + bs.z; vals[3] = a3 + bs.w;
    }

    float s = vals[0] + vals[1] + vals[2] + vals[3];
    red[tid] = s; __syncthreads();
    for (int st = 128; st > 0; st >>= 1) { if (tid < st) red[tid] += red[tid + st]; __syncthreads(); }
    float mu = red[0] * (1.0f / DMODEL);
    __syncthreads();

    float vs = 0.0f;
    #pragma unroll
    for (int i = 0; i < 4; ++i) { float d = vals[i] - mu; vs += d * d; }
    red[tid] = vs; __syncthreads();
    for (int st = 128; st > 0; st >>= 1) { if (tid < st) red[tid] += red[tid + st]; __syncthreads(); }
    float rstd = rsqrtf(red[0] * (1.0f / DMODEL) + LNEPS);

    float4 gv = *reinterpret_cast<const float4*>(g + tid * 4);
    float4 bv = *reinterpret_cast<const float4*>(b + tid * 4);
    float gs[4] = {gv.x, gv.y, gv.z, gv.w};
    float bsc[4] = {bv.x, bv.y, bv.z, bv.w};
    #pragma unroll
    for (int i = 0; i < 4; ++i) {
        float r = (vals[i] - mu) * rstd * gs[i] + bsc[i];
        if (OUTF) out[off + i] = r;
        if (DUAL) outb[off + i] = f2b(r);
    }
}

// ---------------- launch ----------------
extern "C" void kernel_launch(void* const* d_in, const int* in_sizes, int n_in,
                              void* d_out, int out_size, void* d_ws, size_t ws_size,
                              hipStream_t stream)
{
    const float* x    = (const float*)d_in[0];
    const float* wq   = (const float*)d_in[1];
    const float* wk   = (const float*)d_in[2];
    const float* wv   = (const float*)d_in[3];
    const float* wo   = (const float*)d_in[4];
    const float* ln1g = (const float*)d_in[5];
    const float* ln1b = (const float*)d_in[6];
    const float* w1   = (const float*)d_in[7];
    const float* b1   = (const float*)d_in[8];
    const float* w2   = (const float*)d_in[9];
    const float* b2   = (const float*)d_in[10];
    const float* ln2g = (const float*)d_in[11];
    const float* ln2b = (const float*)d_in[12];
    float* out = (float*)d_out;

    char* ws = (char*)d_ws;
    const size_t MB = 1024 * 1024;
    u16* w2T     = (u16*)(ws + 0 * MB);
    u16* w1T     = (u16*)(ws + 8 * MB);
    u16* woT     = (u16*)(ws + 16 * MB);
    u16* wqkvT   = (u16*)(ws + 18 * MB);
    u16* xb      = (u16*)(ws + 24 * MB);
    u16* ff1b    = (u16*)(ws + 24 * MB);
    u16* qkvb    = (u16*)(ws + 28 * MB);
    u16* concatb = (u16*)(ws + 40 * MB);
    f16* Ph      = (f16*)(ws + 44 * MB);
    f16* Fh      = (f16*)(ws + 44 * MB);
    u16* h1b     = (u16*)(ws + 60 * MB);

    const size_t PSTRIDE = (size_t)NTOK * DMODEL;

    dim3 blk(256);

    prep_all<<<dim3(13312), blk, 0, stream>>>(x, wq, wk, wv, wo, w1, w2,
                                              xb, wqkvT, woT, w1T, w2T);

    mfma_gemm<0,0,0,1,1><<<dim3(24, 16), blk, 0, stream>>>(
        xb, DMODEL, wqkvT, DMODEL, qkvb, 3 * DMODEL, DMODEL, nullptr, nullptr, 0, 0);
    flash_attn_mfma<<<dim3(512), dim3(1024), 0, stream>>>(qkvb, concatb);
    mfma_gemm<0,0,0,0,4><<<dim3(8, 16, 4), blk, 0, stream>>>(
        concatb, DMODEL, woT, DMODEL, Ph, DMODEL, 256, nullptr, nullptr, 0, PSTRIDE);
    ln_fuse<4,0,0,1,0><<<dim3(NTOK), blk, 0, stream>>>(
        Ph, PSTRIDE, x, nullptr, ln1g, ln1b, nullptr, h1b);
    mfma_gemm<1,1,0,1,1><<<dim3(32, 16), blk, 0, stream>>>(
        h1b, DMODEL, w1T, DMODEL, ff1b, DFF, DMODEL, b1, nullptr, 0, 0);
    mfma_gemm<0,0,0,0,4><<<dim3(8, 16, 4), blk, 0, stream>>>(
        ff1b, DFF, w2T, DFF, Fh, DMODEL, 1024, nullptr, nullptr, 0, PSTRIDE);
    ln_fuse<4,1,1,0,1><<<dim3(NTOK), blk, 0, stream>>>(
        Fh, PSTRIDE, h1b, b2, ln2g, ln2b, out, nullptr);
}

// Round 18
// 144.826 us; speedup vs baseline: 1.4534x; 1.0311x over previous
//
#include <hip/hip_runtime.h>
#include <math.h>

// TransformerBlock N=2048, D=1024, H=16, DK=DV=64, FF=4096.
// Round 18: XCD-aware block swizzle (T1) on all MFMA GEMMs — contiguous
// block chunks per XCD so shared A/B panels stay in the per-XCD L2
// (all GEMM grids are divisible by 8 -> simple bijective swizzle).
// Flash (16-wave, R17) / prep / LN unchanged.

#define NTOK   2048
#define DMODEL 1024
#define NHEAD  16
#define DHEAD  64
#define DFF    4096
#define LNEPS  1e-5f

typedef unsigned int   u32;
typedef unsigned short u16;
typedef _Float16       f16;
typedef __attribute__((ext_vector_type(8))) short short8;
typedef __attribute__((ext_vector_type(4))) float f32x4;
typedef __attribute__((ext_vector_type(4))) _Float16 f16x4;

__device__ __forceinline__ u16 f2b(float f) {
    u32 b = __float_as_uint(f);
    b += 0x7FFFu + ((b >> 16) & 1u);   // RNE
    return (u16)(b >> 16);
}
__device__ __forceinline__ float b2f(u16 v) {
    return __uint_as_float((u32)v << 16);
}

#define AS1(p) ((const __attribute__((address_space(1))) u32*)(p))
#define AS3(p) ((__attribute__((address_space(3))) u32*)(p))

// ------- bf16 MFMA GEMM, 128x128 tile, BK=64 (2x 32-k panels), dbuf -------
// XCD swizzle: linearized bid remapped so each of the 8 XCDs gets a
// contiguous chunk of block space (all grids here have nwg % 8 == 0).
template<int RELU, int BIAS, int RESID, int OUT_BF16, int SPLITK>
__global__ __launch_bounds__(256) void mfma_gemm(
    const u16* __restrict__ A, int lda,
    const u16* __restrict__ Bt, int ldbt,
    void* __restrict__ Cp, int ldc, int Kc,
    const float* __restrict__ bias,
    const float* __restrict__ resid, int ldr,
    size_t pstride)
{
    __shared__ u16 As[2][2][128 * 32];
    __shared__ u16 Bs[2][2][128 * 32];

    // ---- XCD-aware bijective remap of the flattened block index ----
    const int gx = gridDim.x, gy = gridDim.y;
    const int nwg = gx * gy * gridDim.z;
    int bid = (blockIdx.z * gy + blockIdx.y) * gx + blockIdx.x;
    int swz = (bid & 7) * (nwg >> 3) + (bid >> 3);
    const int bx = swz % gx;
    const int by = (swz / gx) % gy;
    const int bz = swz / (gx * gy);

    const int tid = threadIdx.x;
    const int l = tid & 63, w = tid >> 6;
    const int row0 = by * 128, col0 = bx * 128;
    const int kbase = (SPLITK > 1) ? bz * Kc : 0;

    f32x4 acc[4][4];
    #pragma unroll
    for (int m = 0; m < 4; ++m)
        #pragma unroll
        for (int n = 0; n < 4; ++n)
            acc[m][n] = (f32x4){0.f, 0.f, 0.f, 0.f};

    const int srow = w * 32 + (l >> 2);
    const int skk  = (l & 3) * 8;
    const u16* Ag = A  + (size_t)(row0 + srow) * lda  + kbase + skk;
    const u16* Bg = Bt + (size_t)(col0 + srow) * ldbt + kbase + skk;

    const int fr  = l & 15;
    const int fk  = (l >> 4) * 8;
    const int ar0 = (w >> 1) * 64;
    const int bc0 = (w & 1) * 64;

    auto STAGE = [&](int buf, int k0) {
        char* A0 = (char*)&As[buf][0][0] + w * 2048;
        char* A1 = (char*)&As[buf][1][0] + w * 2048;
        char* B0 = (char*)&Bs[buf][0][0] + w * 2048;
        char* B1 = (char*)&Bs[buf][1][0] + w * 2048;
        __builtin_amdgcn_global_load_lds(AS1(Ag + k0),                          AS3(A0),        16, 0, 0);
        __builtin_amdgcn_global_load_lds(AS1(Ag + k0 + (size_t)16 * lda),       AS3(A0 + 1024), 16, 0, 0);
        __builtin_amdgcn_global_load_lds(AS1(Ag + k0 + 32),                     AS3(A1),        16, 0, 0);
        __builtin_amdgcn_global_load_lds(AS1(Ag + k0 + 32 + (size_t)16 * lda),  AS3(A1 + 1024), 16, 0, 0);
        __builtin_amdgcn_global_load_lds(AS1(Bg + k0),                          AS3(B0),        16, 0, 0);
        __builtin_amdgcn_global_load_lds(AS1(Bg + k0 + (size_t)16 * ldbt),      AS3(B0 + 1024), 16, 0, 0);
        __builtin_amdgcn_global_load_lds(AS1(Bg + k0 + 32),                     AS3(B1),        16, 0, 0);
        __builtin_amdgcn_global_load_lds(AS1(Bg + k0 + 32 + (size_t)16 * ldbt), AS3(B1 + 1024), 16, 0, 0);
    };

    STAGE(0, 0);
    int cur = 0;
    for (int k0 = 0; k0 < Kc; k0 += 64) {
        __syncthreads();
        if (k0 + 64 < Kc) STAGE(cur ^ 1, k0 + 64);

        #pragma unroll
        for (int p = 0; p < 2; ++p) {
            short8 af[4], bfr[4];
            #pragma unroll
            for (int m = 0; m < 4; ++m)
                af[m] = *reinterpret_cast<const short8*>(&As[cur][p][(ar0 + m * 16 + fr) * 32 + fk]);
            #pragma unroll
            for (int n = 0; n < 4; ++n)
                bfr[n] = *reinterpret_cast<const short8*>(&Bs[cur][p][(bc0 + n * 16 + fr) * 32 + fk]);
            #pragma unroll
            for (int m = 0; m < 4; ++m)
                #pragma unroll
                for (int n = 0; n < 4; ++n)
                    acc[m][n] = __builtin_amdgcn_mfma_f32_16x16x32_bf16(af[m], bfr[n], acc[m][n], 0, 0, 0);
        }
        cur ^= 1;
    }

    if (SPLITK > 1) {
        f16* Pp = (f16*)Cp + bz * pstride;
        #pragma unroll
        for (int m = 0; m < 4; ++m)
            #pragma unroll
            for (int n = 0; n < 4; ++n)
                #pragma unroll
                for (int r = 0; r < 4; ++r) {
                    int row = row0 + ar0 + m * 16 + (l >> 4) * 4 + r;
                    int col = col0 + bc0 + n * 16 + (l & 15);
                    Pp[(size_t)row * ldc + col] = (f16)acc[m][n][r];
                }
        return;
    }

    #pragma unroll
    for (int m = 0; m < 4; ++m) {
        #pragma unroll
        for (int n = 0; n < 4; ++n) {
            #pragma unroll
            for (int r = 0; r < 4; ++r) {
                int row = row0 + ar0 + m * 16 + (l >> 4) * 4 + r;
                int col = col0 + bc0 + n * 16 + (l & 15);
                float val = acc[m][n][r];
                if (BIAS)  val += bias[col];
                if (RESID) val += resid[(size_t)row * ldr + col];
                if (RELU)  val = fmaxf(val, 0.0f);
                if (OUT_BF16) ((u16*)Cp)[(size_t)row * ldc + col] = f2b(val);
                else          ((float*)Cp)[(size_t)row * ldc + col] = val;
            }
        }
    }
}

// ---------------- fused prep: x cast + all weight transposes ----------------
__device__ __forceinline__ void transpose_tile32(
    const float* __restrict__ in, int ldin,
    u16* __restrict__ out, int ldout, int r0, int c0)
{
    __shared__ float tile[32][33];
    int tx = threadIdx.x & 31, ty = threadIdx.x >> 5;
    #pragma unroll
    for (int i = 0; i < 4; ++i) {
        int r = ty + i * 8;
        tile[r][tx] = in[(size_t)(r0 + r) * ldin + c0 + tx];
    }
    __syncthreads();
    #pragma unroll
    for (int i = 0; i < 4; ++i) {
        int rr = ty + i * 8;
        out[(size_t)(c0 + rr) * ldout + r0 + tx] = f2b(tile[tx][rr]);
    }
}

__global__ __launch_bounds__(256) void prep_all(
    const float* __restrict__ x,
    const float* __restrict__ wq, const float* __restrict__ wk, const float* __restrict__ wv,
    const float* __restrict__ wo, const float* __restrict__ w1, const float* __restrict__ w2,
    u16* __restrict__ xb, u16* __restrict__ wqkvT, u16* __restrict__ woT,
    u16* __restrict__ w1T, u16* __restrict__ w2T)
{
    int b = blockIdx.x;
    if (b < 1024) {
        int i = (b * 256 + threadIdx.x) * 8;
        float4 v0 = *reinterpret_cast<const float4*>(x + i);
        float4 v1 = *reinterpret_cast<const float4*>(x + i + 4);
        ushort4 o0, o1;
        o0.x = f2b(v0.x); o0.y = f2b(v0.y); o0.z = f2b(v0.z); o0.w = f2b(v0.w);
        o1.x = f2b(v1.x); o1.y = f2b(v1.y); o1.z = f2b(v1.z); o1.w = f2b(v1.w);
        *reinterpret_cast<ushort4*>(xb + i)     = o0;
        *reinterpret_cast<ushort4*>(xb + i + 4) = o1;
    } else if (b < 4096) {
        int u = b - 1024;
        int z = u >> 6, t = u & 63;
        int p = z >> 4, hh = z & 15;
        const float* in = (p == 0 ? wq : p == 1 ? wk : wv) + (size_t)hh * DMODEL * DHEAD;
        u16* out = wqkvT + (size_t)(p * 1024 + hh * 64) * DMODEL;
        transpose_tile32(in, DHEAD, out, DMODEL, (t >> 1) * 32, (t & 1) * 32);
    } else if (b < 5120) {
        int u = b - 4096;
        transpose_tile32(wo, DMODEL, woT, DMODEL, (u >> 5) * 32, (u & 31) * 32);
    } else if (b < 9216) {
        int u = b - 5120;
        transpose_tile32(w1, DFF, w1T, DMODEL, (u >> 7) * 32, (u & 127) * 32);
    } else {
        int u = b - 9216;
        transpose_tile32(w2, DMODEL, w2T, DFF, (u >> 5) * 32, (u & 31) * 32);
    }
}

// ---------------- 16-wave 4-way-split-KV flash attention (R17) ----------
__global__ __launch_bounds__(1024) void flash_attn_mfma(
    const u16* __restrict__ qkvb, u16* __restrict__ concatb)
{
    const int bid = blockIdx.x;
    const int lo = bid & 255;
    int it = lo >> 3;
    int h  = lo & 7;
    if (bid >= 256) { it = 31 - it; h += 8; }

    const u16* qh = qkvb + h * DHEAD;
    const u16* kh = qkvb + DMODEL + h * DHEAD;
    const u16* vh = qkvb + 2 * DMODEL + h * DHEAD;
    const int LDQ = 3 * DMODEL;

    const float SC2  = 0.18033688f;    // 0.125 * log2(e)
    const float THR2 = 11.541560f;     // 8 * log2(e)

    __shared__ u16 Ks[4][64][72];
    __shared__ u16 Vt[4][64][72];

    const int tid = threadIdx.x;
    const int l = tid & 63, w = tid >> 6;
    const int grp = w >> 2, wq = w & 3;
    const int fr = l & 15, fg = l >> 4;

    short8 qf[2];
    {
        const u16* qp = qh + (size_t)(it * 64 + wq * 16 + fr) * LDQ + fg * 8;
        qf[0] = *reinterpret_cast<const short8*>(qp);
        qf[1] = *reinterpret_cast<const short8*>(qp + 32);
    }

    const int kr  = tid >> 2;
    const int kb  = kr >> 6, krl = kr & 63;
    const int kc  = (tid & 3) * 16;
    const int vp  = tid >> 3;
    const int vb  = vp >> 5, vpl = vp & 31;
    const int vc  = (tid & 7) * 8;

    short8 kf0, kf1, vf0, vf1;
    auto PREFETCH = [&](int s) {
        const u16* kg = kh + (size_t)(s * 256 + kr) * LDQ + kc;
        kf0 = *reinterpret_cast<const short8*>(kg);
        kf1 = *reinterpret_cast<const short8*>(kg + 8);
        const u16* vg = vh + (size_t)(s * 256 + 2 * vp) * LDQ + vc;
        vf0 = *reinterpret_cast<const short8*>(vg);
        vf1 = *reinterpret_cast<const short8*>(vg + LDQ);
    };

    f32x4 o[4];
    #pragma unroll
    for (int n = 0; n < 4; ++n) o[n] = (f32x4){0.f, 0.f, 0.f, 0.f};
    float m_run = -INFINITY, l_run = 0.0f;

    const int sA = fr + 16 * ((2 * fg) & 3);
    const int sB = sA + 16;
    const bool hi = (fg >= 2);

    char* VtSb = (char*)&Vt[vb][0][0];

    const int niter = (it >> 2) + 1;
    PREFETCH(0);

    for (int s = 0; s < niter; ++s) {
        __syncthreads();
        *reinterpret_cast<short8*>(&Ks[kb][krl][kc])     = kf0;
        *reinterpret_cast<short8*>(&Ks[kb][krl][kc + 8]) = kf1;
        #pragma unroll
        for (int i = 0; i < 8; ++i) {
            u32 word = (u32)(u16)vf0[i] | ((u32)(u16)vf1[i] << 16);
            int dv = vc + i;
            int off = 144 * dv + 16 * ((vpl >> 2) ^ ((dv >> 3) & 7)) + 4 * (vpl & 3);
            *reinterpret_cast<u32*>(VtSb + off) = word;
        }
        if (s + 1 < niter) PREFETCH(s + 1);
        __syncthreads();

        const int jt = 4 * s + grp;
        if (jt > it) continue;
        const u16 (*KsG)[72] = Ks[grp];
        char* VtG = (char*)&Vt[grp][0][0];

        f32x4 s_[4];
        #pragma unroll
        for (int n = 0; n < 4; ++n) s_[n] = (f32x4){0.f, 0.f, 0.f, 0.f};
        __builtin_amdgcn_s_setprio(1);
        #pragma unroll
        for (int n = 0; n < 4; ++n) {
            #pragma unroll
            for (int ks = 0; ks < 2; ++ks) {
                short8 kfrag = *reinterpret_cast<const short8*>(&KsG[n * 16 + fr][ks * 32 + fg * 8]);
                s_[n] = __builtin_amdgcn_mfma_f32_16x16x32_bf16(kfrag, qf[ks], s_[n], 0, 0, 0);
            }
        }
        __builtin_amdgcn_s_setprio(0);

        const bool diag = (jt == it);
        const int qrow_t = wq * 16 + fr;
        float sv[4][4];
        float pm = -INFINITY;
        #pragma unroll
        for (int n = 0; n < 4; ++n)
            #pragma unroll
            for (int r = 0; r < 4; ++r) {
                float v = s_[n][r] * SC2;
                if (diag && (n * 16 + fg * 4 + r) > qrow_t) v = -INFINITY;
                sv[n][r] = v;
                pm = fmaxf(pm, v);
            }
        pm = fmaxf(pm, __shfl_xor(pm, 16));
        pm = fmaxf(pm, __shfl_xor(pm, 32));
        if (!__all(pm <= m_run + THR2)) {
            float mnew = fmaxf(m_run, pm);
            float corr = exp2f(m_run - mnew);
            l_run *= corr;
            #pragma unroll
            for (int n = 0; n < 4; ++n) {
                o[n][0] *= corr; o[n][1] *= corr; o[n][2] *= corr; o[n][3] *= corr;
            }
            m_run = mnew;
        }
        float rs = 0.0f;
        float pp[4][4];
        #pragma unroll
        for (int n = 0; n < 4; ++n)
            #pragma unroll
            for (int r = 0; r < 4; ++r) {
                float pv = exp2f(sv[n][r] - m_run);
                pp[n][r] = pv;
                rs += pv;
            }
        rs += __shfl_xor(rs, 16);
        rs += __shfl_xor(rs, 32);
        l_run += rs;

        u32 pk[4][2];
        #pragma unroll
        for (int n = 0; n < 4; ++n) {
            pk[n][0] = (__float_as_uint(pp[n][0]) >> 16) | (__float_as_uint(pp[n][1]) & 0xFFFF0000u);
            pk[n][1] = (__float_as_uint(pp[n][2]) >> 16) | (__float_as_uint(pp[n][3]) & 0xFFFF0000u);
        }

        __builtin_amdgcn_s_setprio(1);
        #pragma unroll
        for (int ks = 0; ks < 2; ++ks) {
            u32 a0 = __shfl(pk[2 * ks][0], sA);
            u32 a1 = __shfl(pk[2 * ks][1], sA);
            u32 a2 = __shfl(pk[2 * ks][0], sB);
            u32 a3 = __shfl(pk[2 * ks][1], sB);
            u32 b0 = __shfl(pk[2 * ks + 1][0], sA);
            u32 b1 = __shfl(pk[2 * ks + 1][1], sA);
            u32 b2 = __shfl(pk[2 * ks + 1][0], sB);
            u32 b3 = __shfl(pk[2 * ks + 1][1], sB);
            union { u32 u[4]; short8 s8; } pb;
            pb.u[0] = hi ? b0 : a0;
            pb.u[1] = hi ? b1 : a1;
            pb.u[2] = hi ? b2 : a2;
            pb.u[3] = hi ? b3 : a3;
            #pragma unroll
            for (int n = 0; n < 4; ++n) {
                int dv = n * 16 + fr;
                const short8* vfrag = reinterpret_cast<const short8*>(
                    VtG + 144 * dv + 16 * ((ks * 4 + fg) ^ ((dv >> 3) & 7)));
                o[n] = __builtin_amdgcn_mfma_f32_16x16x32_bf16(*vfrag, pb.s8, o[n], 0, 0, 0);
            }
        }
        __builtin_amdgcn_s_setprio(0);
    }

    // ---- 2-round tree merge via LDS (overlay on Ks; fp32; -inf guarded) ----
    float* mrg = reinterpret_cast<float*>(&Ks[0][0][0]);
    const int slotL = (wq * 64 + l) * 18;
    const int slotH = (256 + wq * 64 + l) * 18;

    auto WRITE = [&](int slot) {
        #pragma unroll
        for (int n = 0; n < 4; ++n)
            #pragma unroll
            for (int r = 0; r < 4; ++r)
                mrg[slot + n * 4 + r] = o[n][r];
        mrg[slot + 16] = m_run;
        mrg[slot + 17] = l_run;
    };
    auto MERGE = [&](int slot) {
        float m2 = mrg[slot + 16];
        if (m2 > -INFINITY) {
            float l2 = mrg[slot + 17];
            float mstar = fmaxf(m_run, m2);
            float cA = exp2f(m_run - mstar);
            float cB = exp2f(m2 - mstar);
            #pragma unroll
            for (int n = 0; n < 4; ++n)
                #pragma unroll
                for (int r = 0; r < 4; ++r)
                    o[n][r] = o[n][r] * cA + mrg[slot + n * 4 + r] * cB;
            l_run = l_run * cA + l2 * cB;
            m_run = mstar;
        }
    };

    __syncthreads();
    if (grp == 1) WRITE(slotL);
    if (grp == 3) WRITE(slotH);
    __syncthreads();
    if (grp == 0) MERGE(slotL);
    if (grp == 2) MERGE(slotH);
    __syncthreads();
    if (grp == 2) WRITE(slotL);
    __syncthreads();
    if (grp == 0) {
        MERGE(slotL);
        float inv = 1.0f / l_run;
        int qrow = it * 64 + wq * 16 + fr;
        #pragma unroll
        for (int n = 0; n < 4; ++n)
            #pragma unroll
            for (int r = 0; r < 4; ++r)
                concatb[(size_t)qrow * DMODEL + h * DHEAD + n * 16 + fg * 4 + r] = f2b(o[n][r] * inv);
    }
}

// ---------------- fused fp16-partial-reduce + LayerNorm ----------------
template<int NPART, int RELUB, int OUTF, int DUAL, int BASEBF16>
__global__ __launch_bounds__(256) void ln_fuse(
    const f16* __restrict__ P, size_t pstride,
    const void* __restrict__ basev,
    const float* __restrict__ bias2,
    const float* __restrict__ g, const float* __restrict__ b,
    float* __restrict__ out, u16* __restrict__ outb)
{
    int row = blockIdx.x, tid = threadIdx.x;
    __shared__ float red[256];
    size_t off = (size_t)row * DMODEL + tid * 4;

    float a0 = 0.f, a1 = 0.f, a2 = 0.f, a3 = 0.f;
    #pragma unroll
    for (int p = 0; p < NPART; ++p) {
        f16x4 t = *reinterpret_cast<const f16x4*>(P + (size_t)p * pstride + off);
        a0 += (float)t.x; a1 += (float)t.y; a2 += (float)t.z; a3 += (float)t.w;
    }
    if (RELUB) {
        float4 bb = *reinterpret_cast<const float4*>(bias2 + tid * 4);
        a0 = fmaxf(a0 + bb.x, 0.0f); a1 = fmaxf(a1 + bb.y, 0.0f);
        a2 = fmaxf(a2 + bb.z, 0.0f); a3 = fmaxf(a3 + bb.w, 0.0f);
    }
    float vals[4];
    if (BASEBF16) {
        ushort4 bs = *reinterpret_cast<const ushort4*>((const u16*)basev + off);
        vals[0] = a0 + b2f(bs.x); vals[1] = a1 + b2f(bs.y);
        vals[2] = a2 + b2f(bs.z); vals[3] = a3 + b2f(bs.w);
    } else {
        float4 bs = *reinterpret_cast<const float4*>((const float*)basev + off);
        vals[0] = a0 + bs.x; vals[1] = a1 + bs.y; vals[2] = a2 + bs.z; vals[3] = a3 + bs.w;
    }

    float s = vals[0] + vals[1] + vals[2] + vals[3];
    red[tid] = s; __syncthreads();
    for (int st = 128; st > 0; st >>= 1) { if (tid < st) red[tid] += red[tid + st]; __syncthreads(); }
    float mu = red[0] * (1.0f / DMODEL);
    __syncthreads();

    float vs = 0.0f;
    #pragma unroll
    for (int i = 0; i < 4; ++i) { float d = vals[i] - mu; vs += d * d; }
    red[tid] = vs; __syncthreads();
    for (int st = 128; st > 0; st >>= 1) { if (tid < st) red[tid] += red[tid + st]; __syncthreads(); }
    float rstd = rsqrtf(red[0] * (1.0f / DMODEL) + LNEPS);

    float4 gv = *reinterpret_cast<const float4*>(g + tid * 4);
    float4 bv = *reinterpret_cast<const float4*>(b + tid * 4);
    float gs[4] = {gv.x, gv.y, gv.z, gv.w};
    float bsc[4] = {bv.x, bv.y, bv.z, bv.w};
    #pragma unroll
    for (int i = 0; i < 4; ++i) {
        float r = (vals[i] - mu) * rstd * gs[i] + bsc[i];
        if (OUTF) out[off + i] = r;
        if (DUAL) outb[off + i] = f2b(r);
    }
}

// ---------------- launch ----------------
extern "C" void kernel_launch(void* const* d_in, const int* in_sizes, int n_in,
                              void* d_out, int out_size, void* d_ws, size_t ws_size,
                              hipStream_t stream)
{
    const float* x    = (const float*)d_in[0];
    const float* wq   = (const float*)d_in[1];
    const float* wk   = (const float*)d_in[2];
    const float* wv   = (const float*)d_in[3];
    const float* wo   = (const float*)d_in[4];
    const float* ln1g = (const float*)d_in[5];
    const float* ln1b = (const float*)d_in[6];
    const float* w1   = (const float*)d_in[7];
    const float* b1   = (const float*)d_in[8];
    const float* w2   = (const float*)d_in[9];
    const float* b2   = (const float*)d_in[10];
    const float* ln2g = (const float*)d_in[11];
    const float* ln2b = (const float*)d_in[12];
    float* out = (float*)d_out;

    char* ws = (char*)d_ws;
    const size_t MB = 1024 * 1024;
    u16* w2T     = (u16*)(ws + 0 * MB);
    u16* w1T     = (u16*)(ws + 8 * MB);
    u16* woT     = (u16*)(ws + 16 * MB);
    u16* wqkvT   = (u16*)(ws + 18 * MB);
    u16* xb      = (u16*)(ws + 24 * MB);
    u16* ff1b    = (u16*)(ws + 24 * MB);
    u16* qkvb    = (u16*)(ws + 28 * MB);
    u16* concatb = (u16*)(ws + 40 * MB);
    f16* Ph      = (f16*)(ws + 44 * MB);
    f16* Fh      = (f16*)(ws + 44 * MB);
    u16* h1b     = (u16*)(ws + 60 * MB);

    const size_t PSTRIDE = (size_t)NTOK * DMODEL;

    dim3 blk(256);

    prep_all<<<dim3(13312), blk, 0, stream>>>(x, wq, wk, wv, wo, w1, w2,
                                              xb, wqkvT, woT, w1T, w2T);

    mfma_gemm<0,0,0,1,1><<<dim3(24, 16), blk, 0, stream>>>(
        xb, DMODEL, wqkvT, DMODEL, qkvb, 3 * DMODEL, DMODEL, nullptr, nullptr, 0, 0);
    flash_attn_mfma<<<dim3(512), dim3(1024), 0, stream>>>(qkvb, concatb);
    mfma_gemm<0,0,0,0,4><<<dim3(8, 16, 4), blk, 0, stream>>>(
        concatb, DMODEL, woT, DMODEL, Ph, DMODEL, 256, nullptr, nullptr, 0, PSTRIDE);
    ln_fuse<4,0,0,1,0><<<dim3(NTOK), blk, 0, stream>>>(
        Ph, PSTRIDE, x, nullptr, ln1g, ln1b, nullptr, h1b);
    mfma_gemm<1,1,0,1,1><<<dim3(32, 16), blk, 0, stream>>>(
        h1b, DMODEL, w1T, DMODEL, ff1b, DFF, DMODEL, b1, nullptr, 0, 0);
    mfma_gemm<0,0,0,0,4><<<dim3(8, 16, 4), blk, 0, stream>>>(
        ff1b, DFF, w2T, DFF, Fh, DMODEL, 1024, nullptr, nullptr, 0, PSTRIDE);
    ln_fuse<4,1,1,0,1><<<dim3(NTOK), blk, 0, stream>>>(
        Fh, PSTRIDE, h1b, b2, ln2g, ln2b, out, nullptr);
}

// Round 19
// 144.775 us; speedup vs baseline: 1.4539x; 1.0004x over previous
//
#include <hip/hip_runtime.h>
#include <math.h>

// TransformerBlock N=2048, D=1024, H=16, DK=DV=64, FF=4096.
// Round 19: flash micro — causal mask hoisted out of the hot loop (uniform
// jt<it vs jt==it branch; mask VALU only on the one diagonal tile per block).
// Everything else = R18 (BK=64 GEMM + XCD swizzle, 16-wave flash, fused prep,
// fp16 split-K partials, fused LN).

#define NTOK   2048
#define DMODEL 1024
#define NHEAD  16
#define DHEAD  64
#define DFF    4096
#define LNEPS  1e-5f

typedef unsigned int   u32;
typedef unsigned short u16;
typedef _Float16       f16;
typedef __attribute__((ext_vector_type(8))) short short8;
typedef __attribute__((ext_vector_type(4))) float f32x4;
typedef __attribute__((ext_vector_type(4))) _Float16 f16x4;

__device__ __forceinline__ u16 f2b(float f) {
    u32 b = __float_as_uint(f);
    b += 0x7FFFu + ((b >> 16) & 1u);   // RNE
    return (u16)(b >> 16);
}
__device__ __forceinline__ float b2f(u16 v) {
    return __uint_as_float((u32)v << 16);
}

#define AS1(p) ((const __attribute__((address_space(1))) u32*)(p))
#define AS3(p) ((__attribute__((address_space(3))) u32*)(p))

// ------- bf16 MFMA GEMM, 128x128 tile, BK=64 (2x 32-k panels), dbuf -------
template<int RELU, int BIAS, int RESID, int OUT_BF16, int SPLITK>
__global__ __launch_bounds__(256) void mfma_gemm(
    const u16* __restrict__ A, int lda,
    const u16* __restrict__ Bt, int ldbt,
    void* __restrict__ Cp, int ldc, int Kc,
    const float* __restrict__ bias,
    const float* __restrict__ resid, int ldr,
    size_t pstride)
{
    __shared__ u16 As[2][2][128 * 32];
    __shared__ u16 Bs[2][2][128 * 32];

    // XCD-aware bijective remap (all grids here have nwg % 8 == 0)
    const int gx = gridDim.x, gy = gridDim.y;
    const int nwg = gx * gy * gridDim.z;
    int bid = (blockIdx.z * gy + blockIdx.y) * gx + blockIdx.x;
    int swz = (bid & 7) * (nwg >> 3) + (bid >> 3);
    const int bx = swz % gx;
    const int by = (swz / gx) % gy;
    const int bz = swz / (gx * gy);

    const int tid = threadIdx.x;
    const int l = tid & 63, w = tid >> 6;
    const int row0 = by * 128, col0 = bx * 128;
    const int kbase = (SPLITK > 1) ? bz * Kc : 0;

    f32x4 acc[4][4];
    #pragma unroll
    for (int m = 0; m < 4; ++m)
        #pragma unroll
        for (int n = 0; n < 4; ++n)
            acc[m][n] = (f32x4){0.f, 0.f, 0.f, 0.f};

    const int srow = w * 32 + (l >> 2);
    const int skk  = (l & 3) * 8;
    const u16* Ag = A  + (size_t)(row0 + srow) * lda  + kbase + skk;
    const u16* Bg = Bt + (size_t)(col0 + srow) * ldbt + kbase + skk;

    const int fr  = l & 15;
    const int fk  = (l >> 4) * 8;
    const int ar0 = (w >> 1) * 64;
    const int bc0 = (w & 1) * 64;

    auto STAGE = [&](int buf, int k0) {
        char* A0 = (char*)&As[buf][0][0] + w * 2048;
        char* A1 = (char*)&As[buf][1][0] + w * 2048;
        char* B0 = (char*)&Bs[buf][0][0] + w * 2048;
        char* B1 = (char*)&Bs[buf][1][0] + w * 2048;
        __builtin_amdgcn_global_load_lds(AS1(Ag + k0),                          AS3(A0),        16, 0, 0);
        __builtin_amdgcn_global_load_lds(AS1(Ag + k0 + (size_t)16 * lda),       AS3(A0 + 1024), 16, 0, 0);
        __builtin_amdgcn_global_load_lds(AS1(Ag + k0 + 32),                     AS3(A1),        16, 0, 0);
        __builtin_amdgcn_global_load_lds(AS1(Ag + k0 + 32 + (size_t)16 * lda),  AS3(A1 + 1024), 16, 0, 0);
        __builtin_amdgcn_global_load_lds(AS1(Bg + k0),                          AS3(B0),        16, 0, 0);
        __builtin_amdgcn_global_load_lds(AS1(Bg + k0 + (size_t)16 * ldbt),      AS3(B0 + 1024), 16, 0, 0);
        __builtin_amdgcn_global_load_lds(AS1(Bg + k0 + 32),                     AS3(B1),        16, 0, 0);
        __builtin_amdgcn_global_load_lds(AS1(Bg + k0 + 32 + (size_t)16 * ldbt), AS3(B1 + 1024), 16, 0, 0);
    };

    STAGE(0, 0);
    int cur = 0;
    for (int k0 = 0; k0 < Kc; k0 += 64) {
        __syncthreads();
        if (k0 + 64 < Kc) STAGE(cur ^ 1, k0 + 64);

        #pragma unroll
        for (int p = 0; p < 2; ++p) {
            short8 af[4], bfr[4];
            #pragma unroll
            for (int m = 0; m < 4; ++m)
                af[m] = *reinterpret_cast<const short8*>(&As[cur][p][(ar0 + m * 16 + fr) * 32 + fk]);
            #pragma unroll
            for (int n = 0; n < 4; ++n)
                bfr[n] = *reinterpret_cast<const short8*>(&Bs[cur][p][(bc0 + n * 16 + fr) * 32 + fk]);
            #pragma unroll
            for (int m = 0; m < 4; ++m)
                #pragma unroll
                for (int n = 0; n < 4; ++n)
                    acc[m][n] = __builtin_amdgcn_mfma_f32_16x16x32_bf16(af[m], bfr[n], acc[m][n], 0, 0, 0);
        }
        cur ^= 1;
    }

    if (SPLITK > 1) {
        f16* Pp = (f16*)Cp + bz * pstride;
        #pragma unroll
        for (int m = 0; m < 4; ++m)
            #pragma unroll
            for (int n = 0; n < 4; ++n)
                #pragma unroll
                for (int r = 0; r < 4; ++r) {
                    int row = row0 + ar0 + m * 16 + (l >> 4) * 4 + r;
                    int col = col0 + bc0 + n * 16 + (l & 15);
                    Pp[(size_t)row * ldc + col] = (f16)acc[m][n][r];
                }
        return;
    }

    #pragma unroll
    for (int m = 0; m < 4; ++m) {
        #pragma unroll
        for (int n = 0; n < 4; ++n) {
            #pragma unroll
            for (int r = 0; r < 4; ++r) {
                int row = row0 + ar0 + m * 16 + (l >> 4) * 4 + r;
                int col = col0 + bc0 + n * 16 + (l & 15);
                float val = acc[m][n][r];
                if (BIAS)  val += bias[col];
                if (RESID) val += resid[(size_t)row * ldr + col];
                if (RELU)  val = fmaxf(val, 0.0f);
                if (OUT_BF16) ((u16*)Cp)[(size_t)row * ldc + col] = f2b(val);
                else          ((float*)Cp)[(size_t)row * ldc + col] = val;
            }
        }
    }
}

// ---------------- fused prep: x cast + all weight transposes ----------------
__device__ __forceinline__ void transpose_tile32(
    const float* __restrict__ in, int ldin,
    u16* __restrict__ out, int ldout, int r0, int c0)
{
    __shared__ float tile[32][33];
    int tx = threadIdx.x & 31, ty = threadIdx.x >> 5;
    #pragma unroll
    for (int i = 0; i < 4; ++i) {
        int r = ty + i * 8;
        tile[r][tx] = in[(size_t)(r0 + r) * ldin + c0 + tx];
    }
    __syncthreads();
    #pragma unroll
    for (int i = 0; i < 4; ++i) {
        int rr = ty + i * 8;
        out[(size_t)(c0 + rr) * ldout + r0 + tx] = f2b(tile[tx][rr]);
    }
}

__global__ __launch_bounds__(256) void prep_all(
    const float* __restrict__ x,
    const float* __restrict__ wq, const float* __restrict__ wk, const float* __restrict__ wv,
    const float* __restrict__ wo, const float* __restrict__ w1, const float* __restrict__ w2,
    u16* __restrict__ xb, u16* __restrict__ wqkvT, u16* __restrict__ woT,
    u16* __restrict__ w1T, u16* __restrict__ w2T)
{
    int b = blockIdx.x;
    if (b < 1024) {
        int i = (b * 256 + threadIdx.x) * 8;
        float4 v0 = *reinterpret_cast<const float4*>(x + i);
        float4 v1 = *reinterpret_cast<const float4*>(x + i + 4);
        ushort4 o0, o1;
        o0.x = f2b(v0.x); o0.y = f2b(v0.y); o0.z = f2b(v0.z); o0.w = f2b(v0.w);
        o1.x = f2b(v1.x); o1.y = f2b(v1.y); o1.z = f2b(v1.z); o1.w = f2b(v1.w);
        *reinterpret_cast<ushort4*>(xb + i)     = o0;
        *reinterpret_cast<ushort4*>(xb + i + 4) = o1;
    } else if (b < 4096) {
        int u = b - 1024;
        int z = u >> 6, t = u & 63;
        int p = z >> 4, hh = z & 15;
        const float* in = (p == 0 ? wq : p == 1 ? wk : wv) + (size_t)hh * DMODEL * DHEAD;
        u16* out = wqkvT + (size_t)(p * 1024 + hh * 64) * DMODEL;
        transpose_tile32(in, DHEAD, out, DMODEL, (t >> 1) * 32, (t & 1) * 32);
    } else if (b < 5120) {
        int u = b - 4096;
        transpose_tile32(wo, DMODEL, woT, DMODEL, (u >> 5) * 32, (u & 31) * 32);
    } else if (b < 9216) {
        int u = b - 5120;
        transpose_tile32(w1, DFF, w1T, DMODEL, (u >> 7) * 32, (u & 127) * 32);
    } else {
        int u = b - 9216;
        transpose_tile32(w2, DMODEL, w2T, DFF, (u >> 5) * 32, (u & 31) * 32);
    }
}

// ---------------- 16-wave 4-way-split-KV flash attention ----------
// R17/R18 structure; causal mask hoisted: uniform jt<it vs jt==it branch.
__global__ __launch_bounds__(1024) void flash_attn_mfma(
    const u16* __restrict__ qkvb, u16* __restrict__ concatb)
{
    const int bid = blockIdx.x;
    const int lo = bid & 255;
    int it = lo >> 3;
    int h  = lo & 7;
    if (bid >= 256) { it = 31 - it; h += 8; }

    const u16* qh = qkvb + h * DHEAD;
    const u16* kh = qkvb + DMODEL + h * DHEAD;
    const u16* vh = qkvb + 2 * DMODEL + h * DHEAD;
    const int LDQ = 3 * DMODEL;

    const float SC2  = 0.18033688f;    // 0.125 * log2(e)
    const float THR2 = 11.541560f;     // 8 * log2(e)

    __shared__ u16 Ks[4][64][72];
    __shared__ u16 Vt[4][64][72];

    const int tid = threadIdx.x;
    const int l = tid & 63, w = tid >> 6;
    const int grp = w >> 2, wq = w & 3;
    const int fr = l & 15, fg = l >> 4;

    short8 qf[2];
    {
        const u16* qp = qh + (size_t)(it * 64 + wq * 16 + fr) * LDQ + fg * 8;
        qf[0] = *reinterpret_cast<const short8*>(qp);
        qf[1] = *reinterpret_cast<const short8*>(qp + 32);
    }

    const int kr  = tid >> 2;
    const int kb  = kr >> 6, krl = kr & 63;
    const int kc  = (tid & 3) * 16;
    const int vp  = tid >> 3;
    const int vb  = vp >> 5, vpl = vp & 31;
    const int vc  = (tid & 7) * 8;

    short8 kf0, kf1, vf0, vf1;
    auto PREFETCH = [&](int s) {
        const u16* kg = kh + (size_t)(s * 256 + kr) * LDQ + kc;
        kf0 = *reinterpret_cast<const short8*>(kg);
        kf1 = *reinterpret_cast<const short8*>(kg + 8);
        const u16* vg = vh + (size_t)(s * 256 + 2 * vp) * LDQ + vc;
        vf0 = *reinterpret_cast<const short8*>(vg);
        vf1 = *reinterpret_cast<const short8*>(vg + LDQ);
    };

    f32x4 o[4];
    #pragma unroll
    for (int n = 0; n < 4; ++n) o[n] = (f32x4){0.f, 0.f, 0.f, 0.f};
    float m_run = -INFINITY, l_run = 0.0f;

    const int sA = fr + 16 * ((2 * fg) & 3);
    const int sB = sA + 16;
    const bool hi = (fg >= 2);

    char* VtSb = (char*)&Vt[vb][0][0];

    // per-tile compute; domask is a literal at each call site -> cloned
    auto TILE = [&](bool domask) {
        const u16 (*KsG)[72] = Ks[grp];
        char* VtG = (char*)&Vt[grp][0][0];

        f32x4 s_[4];
        #pragma unroll
        for (int n = 0; n < 4; ++n) s_[n] = (f32x4){0.f, 0.f, 0.f, 0.f};
        __builtin_amdgcn_s_setprio(1);
        #pragma unroll
        for (int n = 0; n < 4; ++n) {
            #pragma unroll
            for (int ks = 0; ks < 2; ++ks) {
                short8 kfrag = *reinterpret_cast<const short8*>(&KsG[n * 16 + fr][ks * 32 + fg * 8]);
                s_[n] = __builtin_amdgcn_mfma_f32_16x16x32_bf16(kfrag, qf[ks], s_[n], 0, 0, 0);
            }
        }
        __builtin_amdgcn_s_setprio(0);

        const int qrow_t = wq * 16 + fr;
        float sv[4][4];
        float pm = -INFINITY;
        #pragma unroll
        for (int n = 0; n < 4; ++n)
            #pragma unroll
            for (int r = 0; r < 4; ++r) {
                float v = s_[n][r] * SC2;
                if (domask && (n * 16 + fg * 4 + r) > qrow_t) v = -INFINITY;
                sv[n][r] = v;
                pm = fmaxf(pm, v);
            }
        pm = fmaxf(pm, __shfl_xor(pm, 16));
        pm = fmaxf(pm, __shfl_xor(pm, 32));
        if (!__all(pm <= m_run + THR2)) {
            float mnew = fmaxf(m_run, pm);
            float corr = exp2f(m_run - mnew);
            l_run *= corr;
            #pragma unroll
            for (int n = 0; n < 4; ++n) {
                o[n][0] *= corr; o[n][1] *= corr; o[n][2] *= corr; o[n][3] *= corr;
            }
            m_run = mnew;
        }
        float rs = 0.0f;
        float pp[4][4];
        #pragma unroll
        for (int n = 0; n < 4; ++n)
            #pragma unroll
            for (int r = 0; r < 4; ++r) {
                float pv = exp2f(sv[n][r] - m_run);
                pp[n][r] = pv;
                rs += pv;
            }
        rs += __shfl_xor(rs, 16);
        rs += __shfl_xor(rs, 32);
        l_run += rs;

        u32 pk[4][2];
        #pragma unroll
        for (int n = 0; n < 4; ++n) {
            pk[n][0] = (__float_as_uint(pp[n][0]) >> 16) | (__float_as_uint(pp[n][1]) & 0xFFFF0000u);
            pk[n][1] = (__float_as_uint(pp[n][2]) >> 16) | (__float_as_uint(pp[n][3]) & 0xFFFF0000u);
        }

        __builtin_amdgcn_s_setprio(1);
        #pragma unroll
        for (int ks = 0; ks < 2; ++ks) {
            u32 a0 = __shfl(pk[2 * ks][0], sA);
            u32 a1 = __shfl(pk[2 * ks][1], sA);
            u32 a2 = __shfl(pk[2 * ks][0], sB);
            u32 a3 = __shfl(pk[2 * ks][1], sB);
            u32 b0 = __shfl(pk[2 * ks + 1][0], sA);
            u32 b1 = __shfl(pk[2 * ks + 1][1], sA);
            u32 b2 = __shfl(pk[2 * ks + 1][0], sB);
            u32 b3 = __shfl(pk[2 * ks + 1][1], sB);
            union { u32 u[4]; short8 s8; } pb;
            pb.u[0] = hi ? b0 : a0;
            pb.u[1] = hi ? b1 : a1;
            pb.u[2] = hi ? b2 : a2;
            pb.u[3] = hi ? b3 : a3;
            #pragma unroll
            for (int n = 0; n < 4; ++n) {
                int dv = n * 16 + fr;
                const short8* vfrag = reinterpret_cast<const short8*>(
                    VtG + 144 * dv + 16 * ((ks * 4 + fg) ^ ((dv >> 3) & 7)));
                o[n] = __builtin_amdgcn_mfma_f32_16x16x32_bf16(*vfrag, pb.s8, o[n], 0, 0, 0);
            }
        }
        __builtin_amdgcn_s_setprio(0);
    };

    const int niter = (it >> 2) + 1;
    PREFETCH(0);

    for (int s = 0; s < niter; ++s) {
        __syncthreads();
        *reinterpret_cast<short8*>(&Ks[kb][krl][kc])     = kf0;
        *reinterpret_cast<short8*>(&Ks[kb][krl][kc + 8]) = kf1;
        #pragma unroll
        for (int i = 0; i < 8; ++i) {
            u32 word = (u32)(u16)vf0[i] | ((u32)(u16)vf1[i] << 16);
            int dv = vc + i;
            int off = 144 * dv + 16 * ((vpl >> 2) ^ ((dv >> 3) & 7)) + 4 * (vpl & 3);
            *reinterpret_cast<u32*>(VtSb + off) = word;
        }
        if (s + 1 < niter) PREFETCH(s + 1);
        __syncthreads();

        const int jt = 4 * s + grp;
        if (jt < it)       TILE(false);   // hot path: no mask VALU
        else if (jt == it) TILE(true);    // one diagonal tile per block
    }

    // ---- 2-round tree merge via LDS (overlay on Ks; fp32; -inf guarded) ----
    float* mrg = reinterpret_cast<float*>(&Ks[0][0][0]);
    const int slotL = (wq * 64 + l) * 18;
    const int slotH = (256 + wq * 64 + l) * 18;

    auto WRITE = [&](int slot) {
        #pragma unroll
        for (int n = 0; n < 4; ++n)
            #pragma unroll
            for (int r = 0; r < 4; ++r)
                mrg[slot + n * 4 + r] = o[n][r];
        mrg[slot + 16] = m_run;
        mrg[slot + 17] = l_run;
    };
    auto MERGE = [&](int slot) {
        float m2 = mrg[slot + 16];
        if (m2 > -INFINITY) {
            float l2 = mrg[slot + 17];
            float mstar = fmaxf(m_run, m2);
            float cA = exp2f(m_run - mstar);
            float cB = exp2f(m2 - mstar);
            #pragma unroll
            for (int n = 0; n < 4; ++n)
                #pragma unroll
                for (int r = 0; r < 4; ++r)
                    o[n][r] = o[n][r] * cA + mrg[slot + n * 4 + r] * cB;
            l_run = l_run * cA + l2 * cB;
            m_run = mstar;
        }
    };

    __syncthreads();
    if (grp == 1) WRITE(slotL);
    if (grp == 3) WRITE(slotH);
    __syncthreads();
    if (grp == 0) MERGE(slotL);
    if (grp == 2) MERGE(slotH);
    __syncthreads();
    if (grp == 2) WRITE(slotL);
    __syncthreads();
    if (grp == 0) {
        MERGE(slotL);
        float inv = 1.0f / l_run;
        int qrow = it * 64 + wq * 16 + fr;
        #pragma unroll
        for (int n = 0; n < 4; ++n)
            #pragma unroll
            for (int r = 0; r < 4; ++r)
                concatb[(size_t)qrow * DMODEL + h * DHEAD + n * 16 + fg * 4 + r] = f2b(o[n][r] * inv);
    }
}

// ---------------- fused fp16-partial-reduce + LayerNorm ----------------
template<int NPART, int RELUB, int OUTF, int DUAL, int BASEBF16>
__global__ __launch_bounds__(256) void ln_fuse(
    const f16* __restrict__ P, size_t pstride,
    const void* __restrict__ basev,
    const float* __restrict__ bias2,
    const float* __restrict__ g, const float* __restrict__ b,
    float* __restrict__ out, u16* __restrict__ outb)
{
    int row = blockIdx.x, tid = threadIdx.x;
    __shared__ float red[256];
    size_t off = (size_t)row * DMODEL + tid * 4;

    float a0 = 0.f, a1 = 0.f, a2 = 0.f, a3 = 0.f;
    #pragma unroll
    for (int p = 0; p < NPART; ++p) {
        f16x4 t = *reinterpret_cast<const f16x4*>(P + (size_t)p * pstride + off);
        a0 += (float)t.x; a1 += (float)t.y; a2 += (float)t.z; a3 += (float)t.w;
    }
    if (RELUB) {
        float4 bb = *reinterpret_cast<const float4*>(bias2 + tid * 4);
        a0 = fmaxf(a0 + bb.x, 0.0f); a1 = fmaxf(a1 + bb.y, 0.0f);
        a2 = fmaxf(a2 + bb.z, 0.0f); a3 = fmaxf(a3 + bb.w, 0.0f);
    }
    float vals[4];
    if (BASEBF16) {
        ushort4 bs = *reinterpret_cast<const ushort4*>((const u16*)basev + off);
        vals[0] = a0 + b2f(bs.x); vals[1] = a1 + b2f(bs.y);
        vals[2] = a2 + b2f(bs.z); vals[3] = a3 + b2f(bs.w);
    } else {
        float4 bs = *reinterpret_cast<const float4*>((const float*)basev + off);
        vals[0] = a0 + bs.x; vals[1] = a1 + bs.y; vals[2] = a2 + bs.z; vals[3] = a3 + bs.w;
    }

    float s = vals[0] + vals[1] + vals[2] + vals[3];
    red[tid] = s; __syncthreads();
    for (int st = 128; st > 0; st >>= 1) { if (tid < st) red[tid] += red[tid + st]; __syncthreads(); }
    float mu = red[0] * (1.0f / DMODEL);
    __syncthreads();

    float vs = 0.0f;
    #pragma unroll
    for (int i = 0; i < 4; ++i) { float d = vals[i] - mu; vs += d * d; }
    red[tid] = vs; __syncthreads();
    for (int st = 128; st > 0; st >>= 1) { if (tid < st) red[tid] += red[tid + st]; __syncthreads(); }
    float rstd = rsqrtf(red[0] * (1.0f / DMODEL) + LNEPS);

    float4 gv = *reinterpret_cast<const float4*>(g + tid * 4);
    float4 bv = *reinterpret_cast<const float4*>(b + tid * 4);
    float gs[4] = {gv.x, gv.y, gv.z, gv.w};
    float bsc[4] = {bv.x, bv.y, bv.z, bv.w};
    #pragma unroll
    for (int i = 0; i < 4; ++i) {
        float r = (vals[i] - mu) * rstd * gs[i] + bsc[i];
        if (OUTF) out[off + i] = r;
        if (DUAL) outb[off + i] = f2b(r);
    }
}

// ---------------- launch ----------------
extern "C" void kernel_launch(void* const* d_in, const int* in_sizes, int n_in,
                              void* d_out, int out_size, void* d_ws, size_t ws_size,
                              hipStream_t stream)
{
    const float* x    = (const float*)d_in[0];
    const float* wq   = (const float*)d_in[1];
    const float* wk   = (const float*)d_in[2];
    const float* wv   = (const float*)d_in[3];
    const float* wo   = (const float*)d_in[4];
    const float* ln1g = (const float*)d_in[5];
    const float* ln1b = (const float*)d_in[6];
    const float* w1   = (const float*)d_in[7];
    const float* b1   = (const float*)d_in[8];
    const float* w2   = (const float*)d_in[9];
    const float* b2   = (const float*)d_in[10];
    const float* ln2g = (const float*)d_in[11];
    const float* ln2b = (const float*)d_in[12];
    float* out = (float*)d_out;

    char* ws = (char*)d_ws;
    const size_t MB = 1024 * 1024;
    u16* w2T     = (u16*)(ws + 0 * MB);
    u16* w1T     = (u16*)(ws + 8 * MB);
    u16* woT     = (u16*)(ws + 16 * MB);
    u16* wqkvT   = (u16*)(ws + 18 * MB);
    u16* xb      = (u16*)(ws + 24 * MB);
    u16* ff1b    = (u16*)(ws + 24 * MB);
    u16* qkvb    = (u16*)(ws + 28 * MB);
    u16* concatb = (u16*)(ws + 40 * MB);
    f16* Ph      = (f16*)(ws + 44 * MB);
    f16* Fh      = (f16*)(ws + 44 * MB);
    u16* h1b     = (u16*)(ws + 60 * MB);

    const size_t PSTRIDE = (size_t)NTOK * DMODEL;

    dim3 blk(256);

    prep_all<<<dim3(13312), blk, 0, stream>>>(x, wq, wk, wv, wo, w1, w2,
                                              xb, wqkvT, woT, w1T, w2T);

    mfma_gemm<0,0,0,1,1><<<dim3(24, 16), blk, 0, stream>>>(
        xb, DMODEL, wqkvT, DMODEL, qkvb, 3 * DMODEL, DMODEL, nullptr, nullptr, 0, 0);
    flash_attn_mfma<<<dim3(512), dim3(1024), 0, stream>>>(qkvb, concatb);
    mfma_gemm<0,0,0,0,4><<<dim3(8, 16, 4), blk, 0, stream>>>(
        concatb, DMODEL, woT, DMODEL, Ph, DMODEL, 256, nullptr, nullptr, 0, PSTRIDE);
    ln_fuse<4,0,0,1,0><<<dim3(NTOK), blk, 0, stream>>>(
        Ph, PSTRIDE, x, nullptr, ln1g, ln1b, nullptr, h1b);
    mfma_gemm<1,1,0,1,1><<<dim3(32, 16), blk, 0, stream>>>(
        h1b, DMODEL, w1T, DMODEL, ff1b, DFF, DMODEL, b1, nullptr, 0, 0);
    mfma_gemm<0,0,0,0,4><<<dim3(8, 16, 4), blk, 0, stream>>>(
        ff1b, DFF, w2T, DFF, Fh, DMODEL, 1024, nullptr, nullptr, 0, PSTRIDE);
    ln_fuse<4,1,1,0,1><<<dim3(NTOK), blk, 0, stream>>>(
        Fh, PSTRIDE, h1b, b2, ln2g, ln2b, out, nullptr);
}